// Round 3
// baseline (53905.414 us; speedup 1.0000x reference)
//
#include <hip/hip_runtime.h>
#include <math.h>

#define B_ 16
#define T_ 64
#define N_ 512
#define H_ 128
#define P_ 12
#define NH 65536  // N_*H_

// ---------------------------------------------------------------------------
// Lx[b,t,m] = sum_n L[m,n] * x[b,t,n]   (L symmetric)
// ---------------------------------------------------------------------------
__global__ __launch_bounds__(512) void lx_kernel(const float* __restrict__ x,
                                                 const float* __restrict__ L,
                                                 float* __restrict__ Lx) {
    __shared__ __align__(16) float xs[4][N_];
    const int r0 = blockIdx.x * 4;
    const int tid = threadIdx.x;
    for (int j = 0; j < 4; ++j)
        xs[j][tid] = x[(size_t)(r0 + j) * N_ + tid];
    __syncthreads();
    float a0 = 0.f, a1 = 0.f, a2 = 0.f, a3 = 0.f;
    const int m = tid;
#pragma unroll 8
    for (int n = 0; n < N_; ++n) {
        float lv = L[(size_t)n * N_ + m];
        a0 += xs[0][n] * lv;
        a1 += xs[1][n] * lv;
        a2 += xs[2][n] * lv;
        a3 += xs[3][n] * lv;
    }
    Lx[(size_t)(r0 + 0) * N_ + m] = a0;
    Lx[(size_t)(r0 + 1) * N_ + m] = a1;
    Lx[(size_t)(r0 + 2) * N_ + m] = a2;
    Lx[(size_t)(r0 + 3) * N_ + m] = a3;
}

// ===========================================================================
// gc1: Z = L@Hprev (16-row tile, k-split x2) ; ru = sigmoid(Z@W1[1:] + Lx*W1[0] + b1)
//      flat<65536 -> rh = ru*h ; else u = ru
// grid 512 = b(16) x mtile(32, 16 rows), 512 threads, 2 blocks/CU
// ===========================================================================
__global__ __launch_bounds__(512, 4) void gc1_kernel(
    const float* __restrict__ L, const float* __restrict__ Hprev,
    const float* __restrict__ Lx, const float* __restrict__ W1,
    const float* __restrict__ b1, float* __restrict__ rh,
    float* __restrict__ u, int t) {
    __shared__ __align__(16) float Lt[16][520];      // 33280 B (pad 8: broadcast m's hit disjoint bank quads)
    __shared__ __align__(16) float Ht[2][32][H_];    // 32768 B
    __shared__ __align__(16) float Zb[16][H_];       //  8192 B   total 74240 B -> 2 blocks/CU

    const int tid = threadIdx.x;
    const int b = blockIdx.x >> 5;
    const int m0 = (blockIdx.x & 31) * 16;
    const float* __restrict__ Hb = Hprev + (size_t)b * NH;

    // ---- stage L tile once (coalesced, row-major)
    {
        const int lm = tid >> 5, lk0 = (tid & 31) * 4;
#pragma unroll
        for (int s = 0; s < 4; ++s) {
            float4 lv = *(const float4*)&L[(size_t)(m0 + lm) * N_ + lk0 + 128 * s];
            *(float4*)&Lt[lm][lk0 + 128 * s] = lv;
        }
    }
    // ---- stage H chunk 0
    const int hr = tid >> 4, hc = (tid & 15) * 8;
    *(float4*)&Ht[0][hr][hc] = *(const float4*)&Hb[(size_t)hr * H_ + hc];
    *(float4*)&Ht[0][hr][hc + 4] = *(const float4*)&Hb[(size_t)hr * H_ + hc + 4];
    __syncthreads();

    // ---- phase 1: k-split x2, 2m x 4c per thread
    const int g = tid >> 8;         // k-group
    const int gt = tid & 255;
    const int tmg = gt >> 5;        // 0..7
    const int tc = gt & 31;
    const int c0 = tc * 4;
    const int ma = 2 * tmg, mb = ma + 1;

    float accA[4] = {0.f, 0.f, 0.f, 0.f};
    float accB[4] = {0.f, 0.f, 0.f, 0.f};

    for (int c = 0; c < 16; ++c) {
        const int bi = c & 1, bj = bi ^ 1;
        float4 p0, p1;
        if (c < 15) {
            const size_t kb = (size_t)(c + 1) * 32;
            p0 = *(const float4*)&Hb[(kb + hr) * H_ + hc];
            p1 = *(const float4*)&Hb[(kb + hr) * H_ + hc + 4];
        }
#pragma unroll
        for (int k4 = 0; k4 < 4; ++k4) {
            const int lk = g * 16 + k4 * 4;
            const int kg = c * 32 + lk;
            const float4 la = *(const float4*)&Lt[ma][kg];
            const float4 lb = *(const float4*)&Lt[mb][kg];
            const float4 h0 = *(const float4*)&Ht[bi][lk + 0][c0];
            const float4 h1 = *(const float4*)&Ht[bi][lk + 1][c0];
            const float4 h2 = *(const float4*)&Ht[bi][lk + 2][c0];
            const float4 h3 = *(const float4*)&Ht[bi][lk + 3][c0];
            accA[0] += la.x * h0.x + la.y * h1.x + la.z * h2.x + la.w * h3.x;
            accA[1] += la.x * h0.y + la.y * h1.y + la.z * h2.y + la.w * h3.y;
            accA[2] += la.x * h0.z + la.y * h1.z + la.z * h2.z + la.w * h3.z;
            accA[3] += la.x * h0.w + la.y * h1.w + la.z * h2.w + la.w * h3.w;
            accB[0] += lb.x * h0.x + lb.y * h1.x + lb.z * h2.x + lb.w * h3.x;
            accB[1] += lb.x * h0.y + lb.y * h1.y + lb.z * h2.y + lb.w * h3.y;
            accB[2] += lb.x * h0.z + lb.y * h1.z + lb.z * h2.z + lb.w * h3.z;
            accB[3] += lb.x * h0.w + lb.y * h1.w + lb.z * h2.w + lb.w * h3.w;
        }
        if (c < 15) {
            *(float4*)&Ht[bj][hr][hc] = p0;
            *(float4*)&Ht[bj][hr][hc + 4] = p1;
        }
        __syncthreads();
    }

    // merge k-split partials through Zb (8 KB)
    if (g == 1) {
        *(float4*)&Zb[ma][c0] = make_float4(accA[0], accA[1], accA[2], accA[3]);
        *(float4*)&Zb[mb][c0] = make_float4(accB[0], accB[1], accB[2], accB[3]);
    }
    __syncthreads();
    if (g == 0) {
        float4 zA = *(const float4*)&Zb[ma][c0];
        float4 zB = *(const float4*)&Zb[mb][c0];
        *(float4*)&Zb[ma][c0] = make_float4(accA[0] + zA.x, accA[1] + zA.y,
                                            accA[2] + zA.z, accA[3] + zA.w);
        *(float4*)&Zb[mb][c0] = make_float4(accB[0] + zB.x, accB[1] + zB.y,
                                            accB[2] + zB.z, accB[3] + zB.w);
    }
    __syncthreads();

    // ---- phase 2: out = Z @ W1[1:,:]  (W from global/L2, register prefetch, no barriers)
    const int to = tid & 63, tmq = tid >> 6;  // 8 m-groups of 2
    const int o0 = to * 4;
    const int mqa = 2 * tmq, mqb = mqa + 1;
    float aA[4] = {0.f, 0.f, 0.f, 0.f};
    float aB[4] = {0.f, 0.f, 0.f, 0.f};

    float4 w0 = *(const float4*)&W1[(size_t)1 * 256 + o0];
    float4 w1 = *(const float4*)&W1[(size_t)2 * 256 + o0];
    float4 w2 = *(const float4*)&W1[(size_t)3 * 256 + o0];
    float4 w3 = *(const float4*)&W1[(size_t)4 * 256 + o0];
    for (int c4 = 0; c4 < 32; ++c4) {
        float4 n0, n1, n2, n3;
        if (c4 < 31) {
            const size_t r = (size_t)(1 + (c4 + 1) * 4) * 256 + o0;
            n0 = *(const float4*)&W1[r];
            n1 = *(const float4*)&W1[r + 256];
            n2 = *(const float4*)&W1[r + 512];
            n3 = *(const float4*)&W1[r + 768];
        }
        const int ch = c4 * 4;
        const float4 zA = *(const float4*)&Zb[mqa][ch];
        const float4 zB = *(const float4*)&Zb[mqb][ch];
        aA[0] += zA.x * w0.x + zA.y * w1.x + zA.z * w2.x + zA.w * w3.x;
        aA[1] += zA.x * w0.y + zA.y * w1.y + zA.z * w2.y + zA.w * w3.y;
        aA[2] += zA.x * w0.z + zA.y * w1.z + zA.z * w2.z + zA.w * w3.z;
        aA[3] += zA.x * w0.w + zA.y * w1.w + zA.z * w2.w + zA.w * w3.w;
        aB[0] += zB.x * w0.x + zB.y * w1.x + zB.z * w2.x + zB.w * w3.x;
        aB[1] += zB.x * w0.y + zB.y * w1.y + zB.z * w2.y + zB.w * w3.y;
        aB[2] += zB.x * w0.z + zB.y * w1.z + zB.z * w2.z + zB.w * w3.z;
        aB[3] += zB.x * w0.w + zB.y * w1.w + zB.z * w2.w + zB.w * w3.w;
        w0 = n0; w1 = n1; w2 = n2; w3 = n3;
    }

    // ---- epilogue
    const float4 w0r = *(const float4*)&W1[o0];   // row 0 (x channel)
    const float4 bbv = *(const float4*)&b1[o0];
    const float* __restrict__ LxRow = Lx + ((size_t)b * T_ + t) * N_ + m0;
    float* __restrict__ rhB = rh + (size_t)b * NH;
    float* __restrict__ uB = u + (size_t)b * NH;
    const bool isR = (m0 < 256);
    float* accs[2] = {aA, aB};
#pragma unroll
    for (int i = 0; i < 2; ++i) {
        const int mi = mqa + i;
        const float lx = LxRow[mi];
        const float* a2 = accs[i];
        float v0 = a2[0] + lx * w0r.x + bbv.x;
        float v1 = a2[1] + lx * w0r.y + bbv.y;
        float v2 = a2[2] + lx * w0r.z + bbv.z;
        float v3 = a2[3] + lx * w0r.w + bbv.w;
        float s0 = 1.f / (1.f + expf(-v0));
        float s1 = 1.f / (1.f + expf(-v1));
        float s2 = 1.f / (1.f + expf(-v2));
        float s3 = 1.f / (1.f + expf(-v3));
        const int fl = (m0 + mi) * 256 + o0;
        if (isR) {
            float4 hv = *(const float4*)&Hb[fl];
            *(float4*)&rhB[fl] = make_float4(s0 * hv.x, s1 * hv.y, s2 * hv.z, s3 * hv.w);
        } else {
            *(float4*)&uB[fl - NH] = make_float4(s0, s1, s2, s3);
        }
    }
}

// ===========================================================================
// gc2: Z = L@rh ; c = tanh(Z@W2[1:] + Lx*W2[0] + b2) ; hn = u*h + (1-u)*c
//      hs1[b,t,m] = hn[m,:] . att_w1 + att_b1
// ===========================================================================
__global__ __launch_bounds__(512, 4) void gc2_kernel(
    const float* __restrict__ L, const float* __restrict__ Hprev,
    const float* __restrict__ rh, const float* __restrict__ u,
    const float* __restrict__ Lx, const float* __restrict__ W2,
    const float* __restrict__ b2, const float* __restrict__ aw1,
    const float* __restrict__ ab1, float* __restrict__ Hnew,
    float* __restrict__ hs1, int t) {
    __shared__ __align__(16) float Lt[16][520];
    __shared__ __align__(16) float Ht[2][32][H_];
    __shared__ __align__(16) float Zb[16][H_];
    __shared__ __align__(16) float red[16][32];      // +2048 B -> 76288 B total

    const int tid = threadIdx.x;
    const int b = blockIdx.x >> 5;
    const int m0 = (blockIdx.x & 31) * 16;
    const float* __restrict__ Rb = rh + (size_t)b * NH;
    const float* __restrict__ Hb = Hprev + (size_t)b * NH;
    const float* __restrict__ Ub = u + (size_t)b * NH;

    {
        const int lm = tid >> 5, lk0 = (tid & 31) * 4;
#pragma unroll
        for (int s = 0; s < 4; ++s) {
            float4 lv = *(const float4*)&L[(size_t)(m0 + lm) * N_ + lk0 + 128 * s];
            *(float4*)&Lt[lm][lk0 + 128 * s] = lv;
        }
    }
    const int hr = tid >> 4, hc = (tid & 15) * 8;
    *(float4*)&Ht[0][hr][hc] = *(const float4*)&Rb[(size_t)hr * H_ + hc];
    *(float4*)&Ht[0][hr][hc + 4] = *(const float4*)&Rb[(size_t)hr * H_ + hc + 4];
    __syncthreads();

    const int g = tid >> 8;
    const int gt = tid & 255;
    const int tmg = gt >> 5;
    const int tc = gt & 31;
    const int c0 = tc * 4;
    const int ma = 2 * tmg, mb = ma + 1;

    float accA[4] = {0.f, 0.f, 0.f, 0.f};
    float accB[4] = {0.f, 0.f, 0.f, 0.f};

    for (int c = 0; c < 16; ++c) {
        const int bi = c & 1, bj = bi ^ 1;
        float4 p0, p1;
        if (c < 15) {
            const size_t kb = (size_t)(c + 1) * 32;
            p0 = *(const float4*)&Rb[(kb + hr) * H_ + hc];
            p1 = *(const float4*)&Rb[(kb + hr) * H_ + hc + 4];
        }
#pragma unroll
        for (int k4 = 0; k4 < 4; ++k4) {
            const int lk = g * 16 + k4 * 4;
            const int kg = c * 32 + lk;
            const float4 la = *(const float4*)&Lt[ma][kg];
            const float4 lb = *(const float4*)&Lt[mb][kg];
            const float4 h0 = *(const float4*)&Ht[bi][lk + 0][c0];
            const float4 h1 = *(const float4*)&Ht[bi][lk + 1][c0];
            const float4 h2 = *(const float4*)&Ht[bi][lk + 2][c0];
            const float4 h3 = *(const float4*)&Ht[bi][lk + 3][c0];
            accA[0] += la.x * h0.x + la.y * h1.x + la.z * h2.x + la.w * h3.x;
            accA[1] += la.x * h0.y + la.y * h1.y + la.z * h2.y + la.w * h3.y;
            accA[2] += la.x * h0.z + la.y * h1.z + la.z * h2.z + la.w * h3.z;
            accA[3] += la.x * h0.w + la.y * h1.w + la.z * h2.w + la.w * h3.w;
            accB[0] += lb.x * h0.x + lb.y * h1.x + lb.z * h2.x + lb.w * h3.x;
            accB[1] += lb.x * h0.y + lb.y * h1.y + lb.z * h2.y + lb.w * h3.y;
            accB[2] += lb.x * h0.z + lb.y * h1.z + lb.z * h2.z + lb.w * h3.z;
            accB[3] += lb.x * h0.w + lb.y * h1.w + lb.z * h2.w + lb.w * h3.w;
        }
        if (c < 15) {
            *(float4*)&Ht[bj][hr][hc] = p0;
            *(float4*)&Ht[bj][hr][hc + 4] = p1;
        }
        __syncthreads();
    }

    if (g == 1) {
        *(float4*)&Zb[ma][c0] = make_float4(accA[0], accA[1], accA[2], accA[3]);
        *(float4*)&Zb[mb][c0] = make_float4(accB[0], accB[1], accB[2], accB[3]);
    }
    __syncthreads();
    if (g == 0) {
        float4 zA = *(const float4*)&Zb[ma][c0];
        float4 zB = *(const float4*)&Zb[mb][c0];
        *(float4*)&Zb[ma][c0] = make_float4(accA[0] + zA.x, accA[1] + zA.y,
                                            accA[2] + zA.z, accA[3] + zA.w);
        *(float4*)&Zb[mb][c0] = make_float4(accB[0] + zB.x, accB[1] + zB.y,
                                            accB[2] + zB.z, accB[3] + zB.w);
    }
    __syncthreads();

    // ---- phase 2: O=128, 1m x 4o per thread, W2 from global/L2
    const int to = tid & 31, tmq = tid >> 5;   // 16 m-groups of 1
    const int o0 = to * 4;
    float a2[4] = {0.f, 0.f, 0.f, 0.f};

    float4 w0 = *(const float4*)&W2[(size_t)1 * H_ + o0];
    float4 w1 = *(const float4*)&W2[(size_t)2 * H_ + o0];
    float4 w2 = *(const float4*)&W2[(size_t)3 * H_ + o0];
    float4 w3 = *(const float4*)&W2[(size_t)4 * H_ + o0];
    for (int c4 = 0; c4 < 32; ++c4) {
        float4 n0, n1, n2, n3;
        if (c4 < 31) {
            const size_t r = (size_t)(1 + (c4 + 1) * 4) * H_ + o0;
            n0 = *(const float4*)&W2[r];
            n1 = *(const float4*)&W2[r + H_];
            n2 = *(const float4*)&W2[r + 2 * H_];
            n3 = *(const float4*)&W2[r + 3 * H_];
        }
        const int ch = c4 * 4;
        const float4 zv = *(const float4*)&Zb[tmq][ch];
        a2[0] += zv.x * w0.x + zv.y * w1.x + zv.z * w2.x + zv.w * w3.x;
        a2[1] += zv.x * w0.y + zv.y * w1.y + zv.z * w2.y + zv.w * w3.y;
        a2[2] += zv.x * w0.z + zv.y * w1.z + zv.z * w2.z + zv.w * w3.z;
        a2[3] += zv.x * w0.w + zv.y * w1.w + zv.z * w2.w + zv.w * w3.w;
        w0 = n0; w1 = n1; w2 = n2; w3 = n3;
    }

    // ---- epilogue: tanh, GRU blend, hs1 reduction
    const float4 w0r = *(const float4*)&W2[o0];
    const float4 bbv = *(const float4*)&b2[o0];
    const float4 awv = *(const float4*)&aw1[o0];
    const float* __restrict__ LxRow = Lx + ((size_t)b * T_ + t) * N_ + m0;
    float* __restrict__ HnB = Hnew + (size_t)b * NH;
    {
        const int mi = tmq;
        const float lx = LxRow[mi];
        float c0e = tanhf(a2[0] + lx * w0r.x + bbv.x);
        float c1e = tanhf(a2[1] + lx * w0r.y + bbv.y);
        float c2e = tanhf(a2[2] + lx * w0r.z + bbv.z);
        float c3e = tanhf(a2[3] + lx * w0r.w + bbv.w);
        const int fl = (m0 + mi) * H_ + o0;
        float4 uv = *(const float4*)&Ub[fl];
        float4 hp = *(const float4*)&Hb[fl];
        float h0 = uv.x * hp.x + (1.f - uv.x) * c0e;
        float h1 = uv.y * hp.y + (1.f - uv.y) * c1e;
        float h2 = uv.z * hp.z + (1.f - uv.z) * c2e;
        float h3 = uv.w * hp.w + (1.f - uv.w) * c3e;
        *(float4*)&HnB[fl] = make_float4(h0, h1, h2, h3);
        red[mi][to] = h0 * awv.x + h1 * awv.y + h2 * awv.z + h3 * awv.w;
    }
    __syncthreads();
    if (tid < 16) {
        float s = 0.f;
#pragma unroll
        for (int k2 = 0; k2 < 32; ++k2) s += red[tid][k2];
        hs1[((size_t)b * T_ + t) * N_ + m0 + tid] = s + ab1[0];
    }
}

// ---------------------------------------------------------------------------
// beta[b,t] = softmax_t( (hs1@aw2+ab2) * (hs1@aw3+ab3) )
// ---------------------------------------------------------------------------
__global__ __launch_bounds__(64) void att_beta_kernel(
    const float* __restrict__ hs1, const float* __restrict__ aw2,
    const float* __restrict__ aw3, const float* __restrict__ ab2,
    const float* __restrict__ ab3, float* __restrict__ beta) {
    const int b = blockIdx.x;
    const int t = threadIdx.x;
    const float* __restrict__ row = hs1 + ((size_t)b * T_ + t) * N_;
    float f = 0.f, g = 0.f;
    for (int n = 0; n < N_; n += 4) {
        float4 hv = *(const float4*)&row[n];
        float4 w2v = *(const float4*)&aw2[n];
        float4 w3v = *(const float4*)&aw3[n];
        f += hv.x * w2v.x + hv.y * w2v.y + hv.z * w2v.z + hv.w * w2v.w;
        g += hv.x * w3v.x + hv.y * w3v.y + hv.z * w3v.z + hv.w * w3v.w;
    }
    f += ab2[0];
    g += ab3[0];
    float s = f * g;
    float mx = s;
    for (int off = 32; off; off >>= 1) mx = fmaxf(mx, __shfl_xor(mx, off));
    float e = expf(s - mx);
    float sum = e;
    for (int off = 32; off; off >>= 1) sum += __shfl_xor(sum, off);
    beta[b * T_ + t] = e / sum;
}

// ---------------------------------------------------------------------------
// out[b,p,n] = b_out[p] + sum_t beta[b,t]*hs1[b,t,n]*W_out[t,p]
// ---------------------------------------------------------------------------
__global__ __launch_bounds__(256) void att_out_kernel(
    const float* __restrict__ hs1, const float* __restrict__ beta,
    const float* __restrict__ Wout, const float* __restrict__ bout,
    float* __restrict__ out) {
    __shared__ float bs[T_];
    __shared__ float ws[T_][P_];
    const int b = blockIdx.x;
    const int tid = threadIdx.x;
    if (tid < T_) bs[tid] = beta[b * T_ + tid];
    for (int i = tid; i < T_ * P_; i += 256) ws[i / P_][i % P_] = Wout[i];
    __syncthreads();
    for (int nn = 0; nn < 2; ++nn) {
        const int n = tid + nn * 256;
        float acc[P_];
#pragma unroll
        for (int p = 0; p < P_; ++p) acc[p] = bout[p];
        for (int t = 0; t < T_; ++t) {
            float v = bs[t] * hs1[((size_t)b * T_ + t) * N_ + n];
#pragma unroll
            for (int p = 0; p < P_; ++p) acc[p] += v * ws[t][p];
        }
#pragma unroll
        for (int p = 0; p < P_; ++p) out[((size_t)b * P_ + p) * N_ + n] = acc[p];
    }
}

extern "C" void kernel_launch(void* const* d_in, const int* in_sizes, int n_in,
                              void* d_out, int out_size, void* d_ws, size_t ws_size,
                              hipStream_t stream) {
    const float* x = (const float*)d_in[0];
    const float* L = (const float*)d_in[1];
    const float* W1 = (const float*)d_in[2];
    const float* b1 = (const float*)d_in[3];
    const float* W2 = (const float*)d_in[4];
    const float* b2 = (const float*)d_in[5];
    const float* aw1 = (const float*)d_in[6];
    const float* aw2 = (const float*)d_in[7];
    const float* aw3 = (const float*)d_in[8];
    const float* ab1 = (const float*)d_in[9];
    const float* ab2 = (const float*)d_in[10];
    const float* ab3 = (const float*)d_in[11];
    const float* Wout = (const float*)d_in[12];
    const float* bout = (const float*)d_in[13];
    float* out = (float*)d_out;

    float* ws = (float*)d_ws;
    float* Lx = ws;                      // B*T*N
    float* hs1 = Lx + B_ * T_ * N_;      // B*T*N
    float* hb0 = hs1 + B_ * T_ * N_;     // B*N*H
    float* hb1 = hb0 + (size_t)B_ * NH;  // B*N*H
    float* rh = hb1 + (size_t)B_ * NH;   // B*N*H
    float* u = rh + (size_t)B_ * NH;     // B*N*H
    float* beta = u + (size_t)B_ * NH;   // B*T
    (void)in_sizes; (void)n_in; (void)out_size; (void)ws_size;

    hipMemsetAsync(hb0, 0, (size_t)B_ * NH * sizeof(float), stream);
    lx_kernel<<<256, 512, 0, stream>>>(x, L, Lx);

    for (int t = 0; t < T_; ++t) {
        float* hp = (t & 1) ? hb1 : hb0;
        float* hn = (t & 1) ? hb0 : hb1;
        gc1_kernel<<<512, 512, 0, stream>>>(L, hp, Lx, W1, b1, rh, u, t);
        gc2_kernel<<<512, 512, 0, stream>>>(L, hp, rh, u, Lx, W2, b2, aw1, ab1,
                                            hn, hs1, t);
    }
    att_beta_kernel<<<16, 64, 0, stream>>>(hs1, aw2, aw3, ab2, ab3, beta);
    att_out_kernel<<<16, 256, 0, stream>>>(hs1, beta, Wout, bout, out);
}

// Round 4
// 37626.138 us; speedup vs baseline: 1.4327x; 1.4327x over previous
//
#include <hip/hip_runtime.h>
#include <math.h>

#define B_ 16
#define T_ 64
#define N_ 512
#define H_ 128
#define P_ 12
#define NH 65536  // N_*H_

// ---------------------------------------------------------------------------
// Lx[b,t,m] = sum_n L[m,n] * x[b,t,n]   (L symmetric)
// ---------------------------------------------------------------------------
__global__ __launch_bounds__(512) void lx_kernel(const float* __restrict__ x,
                                                 const float* __restrict__ L,
                                                 float* __restrict__ Lx) {
    __shared__ __align__(16) float xs[4][N_];
    const int r0 = blockIdx.x * 4;
    const int tid = threadIdx.x;
    for (int j = 0; j < 4; ++j)
        xs[j][tid] = x[(size_t)(r0 + j) * N_ + tid];
    __syncthreads();
    float a0 = 0.f, a1 = 0.f, a2 = 0.f, a3 = 0.f;
    const int m = tid;
#pragma unroll 8
    for (int n = 0; n < N_; ++n) {
        float lv = L[(size_t)n * N_ + m];
        a0 += xs[0][n] * lv;
        a1 += xs[1][n] * lv;
        a2 += xs[2][n] * lv;
        a3 += xs[3][n] * lv;
    }
    Lx[(size_t)(r0 + 0) * N_ + m] = a0;
    Lx[(size_t)(r0 + 1) * N_ + m] = a1;
    Lx[(size_t)(r0 + 2) * N_ + m] = a2;
    Lx[(size_t)(r0 + 3) * N_ + m] = a3;
}

// ===========================================================================
// gc1: Z = L@Hprev (16-row tile, k-split x2) ; ru = sigmoid(Z@W1[1:] + Lx*W1[0] + b1)
//      flat<65536 -> rh = ru*h ; else u = ru
// grid 512 = b(16) x mtile(32, 16 rows), 512 threads.
// NOTE: plain __launch_bounds__(512) — the (512,4) min-waves clause in a prior
// build forced VGPRs to 64 and spilled the whole inner loop to scratch
// (~1.5 GB HBM/dispatch, 30 ms). Do not re-add it.
// ===========================================================================
__global__ __launch_bounds__(512) void gc1_kernel(
    const float* __restrict__ L, const float* __restrict__ Hprev,
    const float* __restrict__ Lx, const float* __restrict__ W1,
    const float* __restrict__ b1, float* __restrict__ rh,
    float* __restrict__ u, int t) {
    __shared__ __align__(16) float Lt[16][520];      // 33280 B
    __shared__ __align__(16) float Ht[2][32][H_];    // 32768 B
    __shared__ __align__(16) float Zb[16][H_];       //  8192 B   total 74240 B

    const int tid = threadIdx.x;
    const int b = blockIdx.x >> 5;
    const int m0 = (blockIdx.x & 31) * 16;
    const float* __restrict__ Hb = Hprev + (size_t)b * NH;

    // ---- stage L tile once (coalesced, row-major)
    {
        const int lm = tid >> 5, lk0 = (tid & 31) * 4;
#pragma unroll
        for (int s = 0; s < 4; ++s) {
            float4 lv = *(const float4*)&L[(size_t)(m0 + lm) * N_ + lk0 + 128 * s];
            *(float4*)&Lt[lm][lk0 + 128 * s] = lv;
        }
    }
    // ---- stage H chunk 0
    const int hr = tid >> 4, hc = (tid & 15) * 8;
    *(float4*)&Ht[0][hr][hc] = *(const float4*)&Hb[(size_t)hr * H_ + hc];
    *(float4*)&Ht[0][hr][hc + 4] = *(const float4*)&Hb[(size_t)hr * H_ + hc + 4];
    __syncthreads();

    // ---- phase 1: k-split x2, 2m x 4c per thread
    const int g = tid >> 8;         // k-group
    const int gt = tid & 255;
    const int tmg = gt >> 5;        // 0..7
    const int tc = gt & 31;
    const int c0 = tc * 4;
    const int ma = 2 * tmg, mb = ma + 1;

    float accA[4] = {0.f, 0.f, 0.f, 0.f};
    float accB[4] = {0.f, 0.f, 0.f, 0.f};

    for (int c = 0; c < 16; ++c) {
        const int bi = c & 1, bj = bi ^ 1;
        float4 p0, p1;
        if (c < 15) {
            const size_t kb = (size_t)(c + 1) * 32;
            p0 = *(const float4*)&Hb[(kb + hr) * H_ + hc];
            p1 = *(const float4*)&Hb[(kb + hr) * H_ + hc + 4];
        }
#pragma unroll
        for (int k4 = 0; k4 < 4; ++k4) {
            const int lk = g * 16 + k4 * 4;
            const int kg = c * 32 + lk;
            const float4 la = *(const float4*)&Lt[ma][kg];
            const float4 lb = *(const float4*)&Lt[mb][kg];
            const float4 h0 = *(const float4*)&Ht[bi][lk + 0][c0];
            const float4 h1 = *(const float4*)&Ht[bi][lk + 1][c0];
            const float4 h2 = *(const float4*)&Ht[bi][lk + 2][c0];
            const float4 h3 = *(const float4*)&Ht[bi][lk + 3][c0];
            accA[0] += la.x * h0.x + la.y * h1.x + la.z * h2.x + la.w * h3.x;
            accA[1] += la.x * h0.y + la.y * h1.y + la.z * h2.y + la.w * h3.y;
            accA[2] += la.x * h0.z + la.y * h1.z + la.z * h2.z + la.w * h3.z;
            accA[3] += la.x * h0.w + la.y * h1.w + la.z * h2.w + la.w * h3.w;
            accB[0] += lb.x * h0.x + lb.y * h1.x + lb.z * h2.x + lb.w * h3.x;
            accB[1] += lb.x * h0.y + lb.y * h1.y + lb.z * h2.y + lb.w * h3.y;
            accB[2] += lb.x * h0.z + lb.y * h1.z + lb.z * h2.z + lb.w * h3.z;
            accB[3] += lb.x * h0.w + lb.y * h1.w + lb.z * h2.w + lb.w * h3.w;
        }
        if (c < 15) {
            *(float4*)&Ht[bj][hr][hc] = p0;
            *(float4*)&Ht[bj][hr][hc + 4] = p1;
        }
        __syncthreads();
    }

    // merge k-split partials through Zb (8 KB)
    if (g == 1) {
        *(float4*)&Zb[ma][c0] = make_float4(accA[0], accA[1], accA[2], accA[3]);
        *(float4*)&Zb[mb][c0] = make_float4(accB[0], accB[1], accB[2], accB[3]);
    }
    __syncthreads();
    if (g == 0) {
        float4 zA = *(const float4*)&Zb[ma][c0];
        float4 zB = *(const float4*)&Zb[mb][c0];
        *(float4*)&Zb[ma][c0] = make_float4(accA[0] + zA.x, accA[1] + zA.y,
                                            accA[2] + zA.z, accA[3] + zA.w);
        *(float4*)&Zb[mb][c0] = make_float4(accB[0] + zB.x, accB[1] + zB.y,
                                            accB[2] + zB.z, accB[3] + zB.w);
    }
    __syncthreads();

    // ---- phase 2: out = Z @ W1[1:,:]  (W from global/L2, register prefetch, no barriers)
    const int to = tid & 63, tmq = tid >> 6;  // 8 m-groups of 2
    const int o0 = to * 4;
    const int mqa = 2 * tmq, mqb = mqa + 1;
    float aA[4] = {0.f, 0.f, 0.f, 0.f};
    float aB[4] = {0.f, 0.f, 0.f, 0.f};

    float4 w0 = *(const float4*)&W1[(size_t)1 * 256 + o0];
    float4 w1 = *(const float4*)&W1[(size_t)2 * 256 + o0];
    float4 w2 = *(const float4*)&W1[(size_t)3 * 256 + o0];
    float4 w3 = *(const float4*)&W1[(size_t)4 * 256 + o0];
    for (int c4 = 0; c4 < 32; ++c4) {
        float4 n0, n1, n2, n3;
        if (c4 < 31) {
            const size_t r = (size_t)(1 + (c4 + 1) * 4) * 256 + o0;
            n0 = *(const float4*)&W1[r];
            n1 = *(const float4*)&W1[r + 256];
            n2 = *(const float4*)&W1[r + 512];
            n3 = *(const float4*)&W1[r + 768];
        }
        const int ch = c4 * 4;
        const float4 zA = *(const float4*)&Zb[mqa][ch];
        const float4 zB = *(const float4*)&Zb[mqb][ch];
        aA[0] += zA.x * w0.x + zA.y * w1.x + zA.z * w2.x + zA.w * w3.x;
        aA[1] += zA.x * w0.y + zA.y * w1.y + zA.z * w2.y + zA.w * w3.y;
        aA[2] += zA.x * w0.z + zA.y * w1.z + zA.z * w2.z + zA.w * w3.z;
        aA[3] += zA.x * w0.w + zA.y * w1.w + zA.z * w2.w + zA.w * w3.w;
        aB[0] += zB.x * w0.x + zB.y * w1.x + zB.z * w2.x + zB.w * w3.x;
        aB[1] += zB.x * w0.y + zB.y * w1.y + zB.z * w2.y + zB.w * w3.y;
        aB[2] += zB.x * w0.z + zB.y * w1.z + zB.z * w2.z + zB.w * w3.z;
        aB[3] += zB.x * w0.w + zB.y * w1.w + zB.z * w2.w + zB.w * w3.w;
        w0 = n0; w1 = n1; w2 = n2; w3 = n3;
    }

    // ---- epilogue (explicit two-way unroll; no stack-indexed arrays)
    const float4 w0r = *(const float4*)&W1[o0];   // row 0 (x channel)
    const float4 bbv = *(const float4*)&b1[o0];
    const float* __restrict__ LxRow = Lx + ((size_t)b * T_ + t) * N_ + m0;
    float* __restrict__ rhB = rh + (size_t)b * NH;
    float* __restrict__ uB = u + (size_t)b * NH;
    const bool isR = (m0 < 256);

#define GC1_EPI(ACC, MI)                                                      \
    {                                                                         \
        const int mi = (MI);                                                  \
        const float lx = LxRow[mi];                                           \
        float v0 = ACC[0] + lx * w0r.x + bbv.x;                               \
        float v1 = ACC[1] + lx * w0r.y + bbv.y;                               \
        float v2 = ACC[2] + lx * w0r.z + bbv.z;                               \
        float v3 = ACC[3] + lx * w0r.w + bbv.w;                               \
        float s0 = 1.f / (1.f + expf(-v0));                                   \
        float s1 = 1.f / (1.f + expf(-v1));                                   \
        float s2 = 1.f / (1.f + expf(-v2));                                   \
        float s3 = 1.f / (1.f + expf(-v3));                                   \
        const int fl = (m0 + mi) * 256 + o0;                                  \
        if (isR) {                                                            \
            float4 hv = *(const float4*)&Hb[fl];                              \
            *(float4*)&rhB[fl] =                                              \
                make_float4(s0 * hv.x, s1 * hv.y, s2 * hv.z, s3 * hv.w);      \
        } else {                                                              \
            *(float4*)&uB[fl - NH] = make_float4(s0, s1, s2, s3);             \
        }                                                                     \
    }
    GC1_EPI(aA, mqa)
    GC1_EPI(aB, mqb)
#undef GC1_EPI
}

// ===========================================================================
// gc2: Z = L@rh ; c = tanh(Z@W2[1:] + Lx*W2[0] + b2) ; hn = u*h + (1-u)*c
//      hs1[b,t,m] = hn[m,:] . att_w1 + att_b1
// ===========================================================================
__global__ __launch_bounds__(512) void gc2_kernel(
    const float* __restrict__ L, const float* __restrict__ Hprev,
    const float* __restrict__ rh, const float* __restrict__ u,
    const float* __restrict__ Lx, const float* __restrict__ W2,
    const float* __restrict__ b2, const float* __restrict__ aw1,
    const float* __restrict__ ab1, float* __restrict__ Hnew,
    float* __restrict__ hs1, int t) {
    __shared__ __align__(16) float Lt[16][520];
    __shared__ __align__(16) float Ht[2][32][H_];
    __shared__ __align__(16) float Zb[16][H_];
    __shared__ __align__(16) float red[16][32];      // 76288 B total

    const int tid = threadIdx.x;
    const int b = blockIdx.x >> 5;
    const int m0 = (blockIdx.x & 31) * 16;
    const float* __restrict__ Rb = rh + (size_t)b * NH;
    const float* __restrict__ Hb = Hprev + (size_t)b * NH;
    const float* __restrict__ Ub = u + (size_t)b * NH;

    {
        const int lm = tid >> 5, lk0 = (tid & 31) * 4;
#pragma unroll
        for (int s = 0; s < 4; ++s) {
            float4 lv = *(const float4*)&L[(size_t)(m0 + lm) * N_ + lk0 + 128 * s];
            *(float4*)&Lt[lm][lk0 + 128 * s] = lv;
        }
    }
    const int hr = tid >> 4, hc = (tid & 15) * 8;
    *(float4*)&Ht[0][hr][hc] = *(const float4*)&Rb[(size_t)hr * H_ + hc];
    *(float4*)&Ht[0][hr][hc + 4] = *(const float4*)&Rb[(size_t)hr * H_ + hc + 4];
    __syncthreads();

    const int g = tid >> 8;
    const int gt = tid & 255;
    const int tmg = gt >> 5;
    const int tc = gt & 31;
    const int c0 = tc * 4;
    const int ma = 2 * tmg, mb = ma + 1;

    float accA[4] = {0.f, 0.f, 0.f, 0.f};
    float accB[4] = {0.f, 0.f, 0.f, 0.f};

    for (int c = 0; c < 16; ++c) {
        const int bi = c & 1, bj = bi ^ 1;
        float4 p0, p1;
        if (c < 15) {
            const size_t kb = (size_t)(c + 1) * 32;
            p0 = *(const float4*)&Rb[(kb + hr) * H_ + hc];
            p1 = *(const float4*)&Rb[(kb + hr) * H_ + hc + 4];
        }
#pragma unroll
        for (int k4 = 0; k4 < 4; ++k4) {
            const int lk = g * 16 + k4 * 4;
            const int kg = c * 32 + lk;
            const float4 la = *(const float4*)&Lt[ma][kg];
            const float4 lb = *(const float4*)&Lt[mb][kg];
            const float4 h0 = *(const float4*)&Ht[bi][lk + 0][c0];
            const float4 h1 = *(const float4*)&Ht[bi][lk + 1][c0];
            const float4 h2 = *(const float4*)&Ht[bi][lk + 2][c0];
            const float4 h3 = *(const float4*)&Ht[bi][lk + 3][c0];
            accA[0] += la.x * h0.x + la.y * h1.x + la.z * h2.x + la.w * h3.x;
            accA[1] += la.x * h0.y + la.y * h1.y + la.z * h2.y + la.w * h3.y;
            accA[2] += la.x * h0.z + la.y * h1.z + la.z * h2.z + la.w * h3.z;
            accA[3] += la.x * h0.w + la.y * h1.w + la.z * h2.w + la.w * h3.w;
            accB[0] += lb.x * h0.x + lb.y * h1.x + lb.z * h2.x + lb.w * h3.x;
            accB[1] += lb.x * h0.y + lb.y * h1.y + lb.z * h2.y + lb.w * h3.y;
            accB[2] += lb.x * h0.z + lb.y * h1.z + lb.z * h2.z + lb.w * h3.z;
            accB[3] += lb.x * h0.w + lb.y * h1.w + lb.z * h2.w + lb.w * h3.w;
        }
        if (c < 15) {
            *(float4*)&Ht[bj][hr][hc] = p0;
            *(float4*)&Ht[bj][hr][hc + 4] = p1;
        }
        __syncthreads();
    }

    if (g == 1) {
        *(float4*)&Zb[ma][c0] = make_float4(accA[0], accA[1], accA[2], accA[3]);
        *(float4*)&Zb[mb][c0] = make_float4(accB[0], accB[1], accB[2], accB[3]);
    }
    __syncthreads();
    if (g == 0) {
        float4 zA = *(const float4*)&Zb[ma][c0];
        float4 zB = *(const float4*)&Zb[mb][c0];
        *(float4*)&Zb[ma][c0] = make_float4(accA[0] + zA.x, accA[1] + zA.y,
                                            accA[2] + zA.z, accA[3] + zA.w);
        *(float4*)&Zb[mb][c0] = make_float4(accB[0] + zB.x, accB[1] + zB.y,
                                            accB[2] + zB.z, accB[3] + zB.w);
    }
    __syncthreads();

    // ---- phase 2: O=128, 1m x 4o per thread, W2 from global/L2
    const int to = tid & 31, tmq = tid >> 5;   // 16 m-groups of 1
    const int o0 = to * 4;
    float a2[4] = {0.f, 0.f, 0.f, 0.f};

    float4 w0 = *(const float4*)&W2[(size_t)1 * H_ + o0];
    float4 w1 = *(const float4*)&W2[(size_t)2 * H_ + o0];
    float4 w2 = *(const float4*)&W2[(size_t)3 * H_ + o0];
    float4 w3 = *(const float4*)&W2[(size_t)4 * H_ + o0];
    for (int c4 = 0; c4 < 32; ++c4) {
        float4 n0, n1, n2, n3;
        if (c4 < 31) {
            const size_t r = (size_t)(1 + (c4 + 1) * 4) * H_ + o0;
            n0 = *(const float4*)&W2[r];
            n1 = *(const float4*)&W2[r + H_];
            n2 = *(const float4*)&W2[r + 2 * H_];
            n3 = *(const float4*)&W2[r + 3 * H_];
        }
        const int ch = c4 * 4;
        const float4 zv = *(const float4*)&Zb[tmq][ch];
        a2[0] += zv.x * w0.x + zv.y * w1.x + zv.z * w2.x + zv.w * w3.x;
        a2[1] += zv.x * w0.y + zv.y * w1.y + zv.z * w2.y + zv.w * w3.y;
        a2[2] += zv.x * w0.z + zv.y * w1.z + zv.z * w2.z + zv.w * w3.z;
        a2[3] += zv.x * w0.w + zv.y * w1.w + zv.z * w2.w + zv.w * w3.w;
        w0 = n0; w1 = n1; w2 = n2; w3 = n3;
    }

    // ---- epilogue: tanh, GRU blend, hs1 reduction
    const float4 w0r = *(const float4*)&W2[o0];
    const float4 bbv = *(const float4*)&b2[o0];
    const float4 awv = *(const float4*)&aw1[o0];
    const float* __restrict__ LxRow = Lx + ((size_t)b * T_ + t) * N_ + m0;
    float* __restrict__ HnB = Hnew + (size_t)b * NH;
    {
        const int mi = tmq;
        const float lx = LxRow[mi];
        float c0e = tanhf(a2[0] + lx * w0r.x + bbv.x);
        float c1e = tanhf(a2[1] + lx * w0r.y + bbv.y);
        float c2e = tanhf(a2[2] + lx * w0r.z + bbv.z);
        float c3e = tanhf(a2[3] + lx * w0r.w + bbv.w);
        const int fl = (m0 + mi) * H_ + o0;
        float4 uv = *(const float4*)&Ub[fl];
        float4 hp = *(const float4*)&Hb[fl];
        float h0 = uv.x * hp.x + (1.f - uv.x) * c0e;
        float h1 = uv.y * hp.y + (1.f - uv.y) * c1e;
        float h2 = uv.z * hp.z + (1.f - uv.z) * c2e;
        float h3 = uv.w * hp.w + (1.f - uv.w) * c3e;
        *(float4*)&HnB[fl] = make_float4(h0, h1, h2, h3);
        red[mi][to] = h0 * awv.x + h1 * awv.y + h2 * awv.z + h3 * awv.w;
    }
    __syncthreads();
    if (tid < 16) {
        float s = 0.f;
#pragma unroll
        for (int k2 = 0; k2 < 32; ++k2) s += red[tid][k2];
        hs1[((size_t)b * T_ + t) * N_ + m0 + tid] = s + ab1[0];
    }
}

// ---------------------------------------------------------------------------
// beta[b,t] = softmax_t( (hs1@aw2+ab2) * (hs1@aw3+ab3) )
// ---------------------------------------------------------------------------
__global__ __launch_bounds__(64) void att_beta_kernel(
    const float* __restrict__ hs1, const float* __restrict__ aw2,
    const float* __restrict__ aw3, const float* __restrict__ ab2,
    const float* __restrict__ ab3, float* __restrict__ beta) {
    const int b = blockIdx.x;
    const int t = threadIdx.x;
    const float* __restrict__ row = hs1 + ((size_t)b * T_ + t) * N_;
    float f = 0.f, g = 0.f;
    for (int n = 0; n < N_; n += 4) {
        float4 hv = *(const float4*)&row[n];
        float4 w2v = *(const float4*)&aw2[n];
        float4 w3v = *(const float4*)&aw3[n];
        f += hv.x * w2v.x + hv.y * w2v.y + hv.z * w2v.z + hv.w * w2v.w;
        g += hv.x * w3v.x + hv.y * w3v.y + hv.z * w3v.z + hv.w * w3v.w;
    }
    f += ab2[0];
    g += ab3[0];
    float s = f * g;
    float mx = s;
    for (int off = 32; off; off >>= 1) mx = fmaxf(mx, __shfl_xor(mx, off));
    float e = expf(s - mx);
    float sum = e;
    for (int off = 32; off; off >>= 1) sum += __shfl_xor(sum, off);
    beta[b * T_ + t] = e / sum;
}

// ---------------------------------------------------------------------------
// out[b,p,n] = b_out[p] + sum_t beta[b,t]*hs1[b,t,n]*W_out[t,p]
// ---------------------------------------------------------------------------
__global__ __launch_bounds__(256) void att_out_kernel(
    const float* __restrict__ hs1, const float* __restrict__ beta,
    const float* __restrict__ Wout, const float* __restrict__ bout,
    float* __restrict__ out) {
    __shared__ float bs[T_];
    __shared__ float ws[T_][P_];
    const int b = blockIdx.x;
    const int tid = threadIdx.x;
    if (tid < T_) bs[tid] = beta[b * T_ + tid];
    for (int i = tid; i < T_ * P_; i += 256) ws[i / P_][i % P_] = Wout[i];
    __syncthreads();
    for (int nn = 0; nn < 2; ++nn) {
        const int n = tid + nn * 256;
        float acc[P_];
#pragma unroll
        for (int p = 0; p < P_; ++p) acc[p] = bout[p];
        for (int t = 0; t < T_; ++t) {
            float v = bs[t] * hs1[((size_t)b * T_ + t) * N_ + n];
#pragma unroll
            for (int p = 0; p < P_; ++p) acc[p] += v * ws[t][p];
        }
#pragma unroll
        for (int p = 0; p < P_; ++p) out[((size_t)b * P_ + p) * N_ + n] = acc[p];
    }
}

extern "C" void kernel_launch(void* const* d_in, const int* in_sizes, int n_in,
                              void* d_out, int out_size, void* d_ws, size_t ws_size,
                              hipStream_t stream) {
    const float* x = (const float*)d_in[0];
    const float* L = (const float*)d_in[1];
    const float* W1 = (const float*)d_in[2];
    const float* b1 = (const float*)d_in[3];
    const float* W2 = (const float*)d_in[4];
    const float* b2 = (const float*)d_in[5];
    const float* aw1 = (const float*)d_in[6];
    const float* aw2 = (const float*)d_in[7];
    const float* aw3 = (const float*)d_in[8];
    const float* ab1 = (const float*)d_in[9];
    const float* ab2 = (const float*)d_in[10];
    const float* ab3 = (const float*)d_in[11];
    const float* Wout = (const float*)d_in[12];
    const float* bout = (const float*)d_in[13];
    float* out = (float*)d_out;

    float* ws = (float*)d_ws;
    float* Lx = ws;                      // B*T*N
    float* hs1 = Lx + B_ * T_ * N_;      // B*T*N
    float* hb0 = hs1 + B_ * T_ * N_;     // B*N*H
    float* hb1 = hb0 + (size_t)B_ * NH;  // B*N*H
    float* rh = hb1 + (size_t)B_ * NH;   // B*N*H
    float* u = rh + (size_t)B_ * NH;     // B*N*H
    float* beta = u + (size_t)B_ * NH;   // B*T
    (void)in_sizes; (void)n_in; (void)out_size; (void)ws_size;

    hipMemsetAsync(hb0, 0, (size_t)B_ * NH * sizeof(float), stream);
    lx_kernel<<<256, 512, 0, stream>>>(x, L, Lx);

    for (int t = 0; t < T_; ++t) {
        float* hp = (t & 1) ? hb1 : hb0;
        float* hn = (t & 1) ? hb0 : hb1;
        gc1_kernel<<<512, 512, 0, stream>>>(L, hp, Lx, W1, b1, rh, u, t);
        gc2_kernel<<<512, 512, 0, stream>>>(L, hp, rh, u, Lx, W2, b2, aw1, ab1,
                                            hn, hs1, t);
    }
    att_beta_kernel<<<16, 64, 0, stream>>>(hs1, aw2, aw3, ab2, ab3, beta);
    att_out_kernel<<<16, 256, 0, stream>>>(hs1, beta, Wout, bout, out);
}

// Round 5
// 22455.460 us; speedup vs baseline: 2.4005x; 1.6756x over previous
//
#include <hip/hip_runtime.h>
#include <math.h>

#define B_ 16
#define T_ 64
#define N_ 512
#define H_ 128
#define P_ 12
#define NH 65536  // N_*H_

// ---------------------------------------------------------------------------
// Lx[b,t,m] = sum_n L[m,n] * x[b,t,n]   (L symmetric)
// ---------------------------------------------------------------------------
__global__ __launch_bounds__(512) void lx_kernel(const float* __restrict__ x,
                                                 const float* __restrict__ L,
                                                 float* __restrict__ Lx) {
    __shared__ __align__(16) float xs[4][N_];
    const int r0 = blockIdx.x * 4;
    const int tid = threadIdx.x;
    for (int j = 0; j < 4; ++j)
        xs[j][tid] = x[(size_t)(r0 + j) * N_ + tid];
    __syncthreads();
    float a0 = 0.f, a1 = 0.f, a2 = 0.f, a3 = 0.f;
    const int m = tid;
#pragma unroll 8
    for (int n = 0; n < N_; ++n) {
        float lv = L[(size_t)n * N_ + m];
        a0 += xs[0][n] * lv;
        a1 += xs[1][n] * lv;
        a2 += xs[2][n] * lv;
        a3 += xs[3][n] * lv;
    }
    Lx[(size_t)(r0 + 0) * N_ + m] = a0;
    Lx[(size_t)(r0 + 1) * N_ + m] = a1;
    Lx[(size_t)(r0 + 2) * N_ + m] = a2;
    Lx[(size_t)(r0 + 3) * N_ + m] = a3;
}

// ===========================================================================
// gc1: Z = L@Hprev (16-row tile, k-split x2) ; ru = sigmoid(Z@W1[1:] + Lx*W1[0] + b1)
//      flat<65536 -> rh = ru*h ; else u = ru
// grid 512 = b(16) x mtile(32 of 16 rows), 512 threads, LDS 74240 B -> 2 blocks/CU.
// NOTE 1: plain __launch_bounds__(512) — a (512,4) min-waves clause forced
//   VGPRs to 64 and spilled everything to scratch (30 ms dispatches).
// NOTE 2: W1 MUST be staged through LDS (read once per block). Streaming W
//   from global per-thread (rounds 3/4) put ~0.5 GB/dispatch of L2 requests,
//   thrashed the 4 MB per-XCD L2, and ran 100x slower.
// ===========================================================================
__global__ __launch_bounds__(512) void gc1_kernel(
    const float* __restrict__ L, const float* __restrict__ Hprev,
    const float* __restrict__ Lx, const float* __restrict__ W1,
    const float* __restrict__ b1, float* __restrict__ rh,
    float* __restrict__ u, int t) {
    union LW {
        float Lt[16][520];   // 33280 B, row-major: stores coalesced, reads broadcast
        float Wt[32][260];   // 33280 B, phase-2 W chunk
    };
    __shared__ __align__(16) LW sm;
    __shared__ __align__(16) float Ht[2][32][H_];    // 32768 B
    __shared__ __align__(16) float Zb[16][H_];       //  8192 B

    const int tid = threadIdx.x;
    const int b = blockIdx.x >> 5;
    const int m0 = (blockIdx.x & 31) * 16;
    const float* __restrict__ Hb = Hprev + (size_t)b * NH;

    // ---- stage L tile once (coalesced, row-major)
    {
        const int lm = tid >> 5, lk0 = (tid & 31) * 4;
#pragma unroll
        for (int s = 0; s < 4; ++s) {
            float4 lv = *(const float4*)&L[(size_t)(m0 + lm) * N_ + lk0 + 128 * s];
            *(float4*)&sm.Lt[lm][lk0 + 128 * s] = lv;
        }
    }
    // ---- stage H chunk 0
    const int hr = tid >> 4, hc = (tid & 15) * 8;
    *(float4*)&Ht[0][hr][hc] = *(const float4*)&Hb[(size_t)hr * H_ + hc];
    *(float4*)&Ht[0][hr][hc + 4] = *(const float4*)&Hb[(size_t)hr * H_ + hc + 4];
    __syncthreads();

    // ---- phase 1: k-split x2, 2m x 4c per thread
    const int g = tid >> 8;         // k-group
    const int gt = tid & 255;
    const int tmg = gt >> 5;        // 0..7
    const int tc = gt & 31;
    const int c0 = tc * 4;
    const int ma = 2 * tmg, mb = ma + 1;

    float accA[4] = {0.f, 0.f, 0.f, 0.f};
    float accB[4] = {0.f, 0.f, 0.f, 0.f};

    for (int c = 0; c < 16; ++c) {
        const int bi = c & 1, bj = bi ^ 1;
        float4 p0, p1;
        if (c < 15) {
            const size_t kb = (size_t)(c + 1) * 32;
            p0 = *(const float4*)&Hb[(kb + hr) * H_ + hc];
            p1 = *(const float4*)&Hb[(kb + hr) * H_ + hc + 4];
        }
#pragma unroll
        for (int k4 = 0; k4 < 4; ++k4) {
            const int lk = g * 16 + k4 * 4;
            const int kg = c * 32 + lk;
            const float4 la = *(const float4*)&sm.Lt[ma][kg];
            const float4 lb = *(const float4*)&sm.Lt[mb][kg];
            const float4 h0 = *(const float4*)&Ht[bi][lk + 0][c0];
            const float4 h1 = *(const float4*)&Ht[bi][lk + 1][c0];
            const float4 h2 = *(const float4*)&Ht[bi][lk + 2][c0];
            const float4 h3 = *(const float4*)&Ht[bi][lk + 3][c0];
            accA[0] += la.x * h0.x + la.y * h1.x + la.z * h2.x + la.w * h3.x;
            accA[1] += la.x * h0.y + la.y * h1.y + la.z * h2.y + la.w * h3.y;
            accA[2] += la.x * h0.z + la.y * h1.z + la.z * h2.z + la.w * h3.z;
            accA[3] += la.x * h0.w + la.y * h1.w + la.z * h2.w + la.w * h3.w;
            accB[0] += lb.x * h0.x + lb.y * h1.x + lb.z * h2.x + lb.w * h3.x;
            accB[1] += lb.x * h0.y + lb.y * h1.y + lb.z * h2.y + lb.w * h3.y;
            accB[2] += lb.x * h0.z + lb.y * h1.z + lb.z * h2.z + lb.w * h3.z;
            accB[3] += lb.x * h0.w + lb.y * h1.w + lb.z * h2.w + lb.w * h3.w;
        }
        if (c < 15) {
            *(float4*)&Ht[bj][hr][hc] = p0;
            *(float4*)&Ht[bj][hr][hc + 4] = p1;
        }
        __syncthreads();
    }

    // merge k-split partials through Zb
    if (g == 1) {
        *(float4*)&Zb[ma][c0] = make_float4(accA[0], accA[1], accA[2], accA[3]);
        *(float4*)&Zb[mb][c0] = make_float4(accB[0], accB[1], accB[2], accB[3]);
    }
    __syncthreads();
    if (g == 0) {
        float4 zA = *(const float4*)&Zb[ma][c0];
        float4 zB = *(const float4*)&Zb[mb][c0];
        *(float4*)&Zb[ma][c0] = make_float4(accA[0] + zA.x, accA[1] + zA.y,
                                            accA[2] + zA.z, accA[3] + zA.w);
        *(float4*)&Zb[mb][c0] = make_float4(accB[0] + zB.x, accB[1] + zB.y,
                                            accB[2] + zB.z, accB[3] + zB.w);
    }
    __syncthreads();

    // ---- phase 2: out = Z @ W1[1:,:]  (W staged in LDS, 4 chunks of 32 ch)
    const int to = tid & 63, tmq = tid >> 6;  // 8 m-groups of 2
    const int o0 = to * 4;
    const int mqa = 2 * tmq, mqb = mqa + 1;
    float aA[4] = {0.f, 0.f, 0.f, 0.f};
    float aB[4] = {0.f, 0.f, 0.f, 0.f};
    const int wr = tid >> 4, wc = (tid & 15) * 16;

    for (int c4 = 0; c4 < 4; ++c4) {
#pragma unroll
        for (int jj = 0; jj < 4; ++jj)
            *(float4*)&sm.Wt[wr][wc + 4 * jj] =
                *(const float4*)&W1[(size_t)(1 + c4 * 32 + wr) * 256 + wc + 4 * jj];
        __syncthreads();
#pragma unroll
        for (int ch4 = 0; ch4 < 8; ++ch4) {
            const float4 w0v = *(const float4*)&sm.Wt[ch4 * 4 + 0][o0];
            const float4 w1v = *(const float4*)&sm.Wt[ch4 * 4 + 1][o0];
            const float4 w2v = *(const float4*)&sm.Wt[ch4 * 4 + 2][o0];
            const float4 w3v = *(const float4*)&sm.Wt[ch4 * 4 + 3][o0];
            const int ch = c4 * 32 + ch4 * 4;
            const float4 zA = *(const float4*)&Zb[mqa][ch];
            const float4 zB = *(const float4*)&Zb[mqb][ch];
            aA[0] += zA.x * w0v.x + zA.y * w1v.x + zA.z * w2v.x + zA.w * w3v.x;
            aA[1] += zA.x * w0v.y + zA.y * w1v.y + zA.z * w2v.y + zA.w * w3v.y;
            aA[2] += zA.x * w0v.z + zA.y * w1v.z + zA.z * w2v.z + zA.w * w3v.z;
            aA[3] += zA.x * w0v.w + zA.y * w1v.w + zA.z * w2v.w + zA.w * w3v.w;
            aB[0] += zB.x * w0v.x + zB.y * w1v.x + zB.z * w2v.x + zB.w * w3v.x;
            aB[1] += zB.x * w0v.y + zB.y * w1v.y + zB.z * w2v.y + zB.w * w3v.y;
            aB[2] += zB.x * w0v.z + zB.y * w1v.z + zB.z * w2v.z + zB.w * w3v.z;
            aB[3] += zB.x * w0v.w + zB.y * w1v.w + zB.z * w2v.w + zB.w * w3v.w;
        }
        __syncthreads();
    }

    // ---- epilogue (verified; explicit two-way unroll, no stack arrays)
    const float4 w0r = *(const float4*)&W1[o0];   // row 0 (x channel)
    const float4 bbv = *(const float4*)&b1[o0];
    const float* __restrict__ LxRow = Lx + ((size_t)b * T_ + t) * N_ + m0;
    float* __restrict__ rhB = rh + (size_t)b * NH;
    float* __restrict__ uB = u + (size_t)b * NH;
    const bool isR = (m0 < 256);

#define GC1_EPI(ACC, MI)                                                      \
    {                                                                         \
        const int mi = (MI);                                                  \
        const float lx = LxRow[mi];                                           \
        float v0 = ACC[0] + lx * w0r.x + bbv.x;                               \
        float v1 = ACC[1] + lx * w0r.y + bbv.y;                               \
        float v2 = ACC[2] + lx * w0r.z + bbv.z;                               \
        float v3 = ACC[3] + lx * w0r.w + bbv.w;                               \
        float s0 = 1.f / (1.f + expf(-v0));                                   \
        float s1 = 1.f / (1.f + expf(-v1));                                   \
        float s2 = 1.f / (1.f + expf(-v2));                                   \
        float s3 = 1.f / (1.f + expf(-v3));                                   \
        const int fl = (m0 + mi) * 256 + o0;                                  \
        if (isR) {                                                            \
            float4 hv = *(const float4*)&Hb[fl];                              \
            *(float4*)&rhB[fl] =                                              \
                make_float4(s0 * hv.x, s1 * hv.y, s2 * hv.z, s3 * hv.w);      \
        } else {                                                              \
            *(float4*)&uB[fl - NH] = make_float4(s0, s1, s2, s3);             \
        }                                                                     \
    }
    GC1_EPI(aA, mqa)
    GC1_EPI(aB, mqb)
#undef GC1_EPI
}

// ===========================================================================
// gc2: Z = L@rh ; c = tanh(Z@W2[1:] + Lx*W2[0] + b2) ; hn = u*h + (1-u)*c
//      hs1[b,t,m] = hn[m,:] . att_w1 + att_b1
// Same structure as gc1; O=128. LDS 76288 B -> 2 blocks/CU.
// ===========================================================================
__global__ __launch_bounds__(512) void gc2_kernel(
    const float* __restrict__ L, const float* __restrict__ Hprev,
    const float* __restrict__ rh, const float* __restrict__ u,
    const float* __restrict__ Lx, const float* __restrict__ W2,
    const float* __restrict__ b2, const float* __restrict__ aw1,
    const float* __restrict__ ab1, float* __restrict__ Hnew,
    float* __restrict__ hs1, int t) {
    union LW {
        float Lt[16][520];   // 33280 B
        float Wt[32][132];   // 16896 B
    };
    __shared__ __align__(16) LW sm;
    __shared__ __align__(16) float Ht[2][32][H_];    // 32768 B
    __shared__ __align__(16) float Zb[16][H_];       //  8192 B
    __shared__ __align__(16) float red[16][32];      //  2048 B

    const int tid = threadIdx.x;
    const int b = blockIdx.x >> 5;
    const int m0 = (blockIdx.x & 31) * 16;
    const float* __restrict__ Rb = rh + (size_t)b * NH;
    const float* __restrict__ Hb = Hprev + (size_t)b * NH;
    const float* __restrict__ Ub = u + (size_t)b * NH;

    {
        const int lm = tid >> 5, lk0 = (tid & 31) * 4;
#pragma unroll
        for (int s = 0; s < 4; ++s) {
            float4 lv = *(const float4*)&L[(size_t)(m0 + lm) * N_ + lk0 + 128 * s];
            *(float4*)&sm.Lt[lm][lk0 + 128 * s] = lv;
        }
    }
    const int hr = tid >> 4, hc = (tid & 15) * 8;
    *(float4*)&Ht[0][hr][hc] = *(const float4*)&Rb[(size_t)hr * H_ + hc];
    *(float4*)&Ht[0][hr][hc + 4] = *(const float4*)&Rb[(size_t)hr * H_ + hc + 4];
    __syncthreads();

    const int g = tid >> 8;
    const int gt = tid & 255;
    const int tmg = gt >> 5;
    const int tc = gt & 31;
    const int c0 = tc * 4;
    const int ma = 2 * tmg, mb = ma + 1;

    float accA[4] = {0.f, 0.f, 0.f, 0.f};
    float accB[4] = {0.f, 0.f, 0.f, 0.f};

    for (int c = 0; c < 16; ++c) {
        const int bi = c & 1, bj = bi ^ 1;
        float4 p0, p1;
        if (c < 15) {
            const size_t kb = (size_t)(c + 1) * 32;
            p0 = *(const float4*)&Rb[(kb + hr) * H_ + hc];
            p1 = *(const float4*)&Rb[(kb + hr) * H_ + hc + 4];
        }
#pragma unroll
        for (int k4 = 0; k4 < 4; ++k4) {
            const int lk = g * 16 + k4 * 4;
            const int kg = c * 32 + lk;
            const float4 la = *(const float4*)&sm.Lt[ma][kg];
            const float4 lb = *(const float4*)&sm.Lt[mb][kg];
            const float4 h0 = *(const float4*)&Ht[bi][lk + 0][c0];
            const float4 h1 = *(const float4*)&Ht[bi][lk + 1][c0];
            const float4 h2 = *(const float4*)&Ht[bi][lk + 2][c0];
            const float4 h3 = *(const float4*)&Ht[bi][lk + 3][c0];
            accA[0] += la.x * h0.x + la.y * h1.x + la.z * h2.x + la.w * h3.x;
            accA[1] += la.x * h0.y + la.y * h1.y + la.z * h2.y + la.w * h3.y;
            accA[2] += la.x * h0.z + la.y * h1.z + la.z * h2.z + la.w * h3.z;
            accA[3] += la.x * h0.w + la.y * h1.w + la.z * h2.w + la.w * h3.w;
            accB[0] += lb.x * h0.x + lb.y * h1.x + lb.z * h2.x + lb.w * h3.x;
            accB[1] += lb.x * h0.y + lb.y * h1.y + lb.z * h2.y + lb.w * h3.y;
            accB[2] += lb.x * h0.z + lb.y * h1.z + lb.z * h2.z + lb.w * h3.z;
            accB[3] += lb.x * h0.w + lb.y * h1.w + lb.z * h2.w + lb.w * h3.w;
        }
        if (c < 15) {
            *(float4*)&Ht[bj][hr][hc] = p0;
            *(float4*)&Ht[bj][hr][hc + 4] = p1;
        }
        __syncthreads();
    }

    if (g == 1) {
        *(float4*)&Zb[ma][c0] = make_float4(accA[0], accA[1], accA[2], accA[3]);
        *(float4*)&Zb[mb][c0] = make_float4(accB[0], accB[1], accB[2], accB[3]);
    }
    __syncthreads();
    if (g == 0) {
        float4 zA = *(const float4*)&Zb[ma][c0];
        float4 zB = *(const float4*)&Zb[mb][c0];
        *(float4*)&Zb[ma][c0] = make_float4(accA[0] + zA.x, accA[1] + zA.y,
                                            accA[2] + zA.z, accA[3] + zA.w);
        *(float4*)&Zb[mb][c0] = make_float4(accB[0] + zB.x, accB[1] + zB.y,
                                            accB[2] + zB.z, accB[3] + zB.w);
    }
    __syncthreads();

    // ---- phase 2: O=128, 1m x 4o per thread, W2 staged in LDS chunks
    const int to = tid & 31, tmq = tid >> 5;   // 16 m-groups of 1
    const int o0 = to * 4;
    float a2[4] = {0.f, 0.f, 0.f, 0.f};
    const int wr = tid >> 4, wc = (tid & 15) * 8;

    for (int c4 = 0; c4 < 4; ++c4) {
#pragma unroll
        for (int jj = 0; jj < 2; ++jj)
            *(float4*)&sm.Wt[wr][wc + 4 * jj] =
                *(const float4*)&W2[(size_t)(1 + c4 * 32 + wr) * H_ + wc + 4 * jj];
        __syncthreads();
#pragma unroll
        for (int ch4 = 0; ch4 < 8; ++ch4) {
            const float4 w0v = *(const float4*)&sm.Wt[ch4 * 4 + 0][o0];
            const float4 w1v = *(const float4*)&sm.Wt[ch4 * 4 + 1][o0];
            const float4 w2v = *(const float4*)&sm.Wt[ch4 * 4 + 2][o0];
            const float4 w3v = *(const float4*)&sm.Wt[ch4 * 4 + 3][o0];
            const float4 zv = *(const float4*)&Zb[tmq][c4 * 32 + ch4 * 4];
            a2[0] += zv.x * w0v.x + zv.y * w1v.x + zv.z * w2v.x + zv.w * w3v.x;
            a2[1] += zv.x * w0v.y + zv.y * w1v.y + zv.z * w2v.y + zv.w * w3v.y;
            a2[2] += zv.x * w0v.z + zv.y * w1v.z + zv.z * w2v.z + zv.w * w3v.z;
            a2[3] += zv.x * w0v.w + zv.y * w1v.w + zv.z * w2v.w + zv.w * w3v.w;
        }
        __syncthreads();
    }

    // ---- epilogue: tanh, GRU blend, hs1 reduction (verified)
    const float4 w0r = *(const float4*)&W2[o0];
    const float4 bbv = *(const float4*)&b2[o0];
    const float4 awv = *(const float4*)&aw1[o0];
    const float* __restrict__ LxRow = Lx + ((size_t)b * T_ + t) * N_ + m0;
    float* __restrict__ HnB = Hnew + (size_t)b * NH;
    {
        const int mi = tmq;
        const float lx = LxRow[mi];
        float c0e = tanhf(a2[0] + lx * w0r.x + bbv.x);
        float c1e = tanhf(a2[1] + lx * w0r.y + bbv.y);
        float c2e = tanhf(a2[2] + lx * w0r.z + bbv.z);
        float c3e = tanhf(a2[3] + lx * w0r.w + bbv.w);
        const int fl = (m0 + mi) * H_ + o0;
        float4 uv = *(const float4*)&Ub[fl];
        float4 hp = *(const float4*)&Hb[fl];
        float h0 = uv.x * hp.x + (1.f - uv.x) * c0e;
        float h1 = uv.y * hp.y + (1.f - uv.y) * c1e;
        float h2 = uv.z * hp.z + (1.f - uv.z) * c2e;
        float h3 = uv.w * hp.w + (1.f - uv.w) * c3e;
        *(float4*)&HnB[fl] = make_float4(h0, h1, h2, h3);
        red[mi][to] = h0 * awv.x + h1 * awv.y + h2 * awv.z + h3 * awv.w;
    }
    __syncthreads();
    if (tid < 16) {
        float s = 0.f;
#pragma unroll
        for (int k2 = 0; k2 < 32; ++k2) s += red[tid][k2];
        hs1[((size_t)b * T_ + t) * N_ + m0 + tid] = s + ab1[0];
    }
}

// ---------------------------------------------------------------------------
// beta[b,t] = softmax_t( (hs1@aw2+ab2) * (hs1@aw3+ab3) )
// ---------------------------------------------------------------------------
__global__ __launch_bounds__(64) void att_beta_kernel(
    const float* __restrict__ hs1, const float* __restrict__ aw2,
    const float* __restrict__ aw3, const float* __restrict__ ab2,
    const float* __restrict__ ab3, float* __restrict__ beta) {
    const int b = blockIdx.x;
    const int t = threadIdx.x;
    const float* __restrict__ row = hs1 + ((size_t)b * T_ + t) * N_;
    float f = 0.f, g = 0.f;
    for (int n = 0; n < N_; n += 4) {
        float4 hv = *(const float4*)&row[n];
        float4 w2v = *(const float4*)&aw2[n];
        float4 w3v = *(const float4*)&aw3[n];
        f += hv.x * w2v.x + hv.y * w2v.y + hv.z * w2v.z + hv.w * w2v.w;
        g += hv.x * w3v.x + hv.y * w3v.y + hv.z * w3v.z + hv.w * w3v.w;
    }
    f += ab2[0];
    g += ab3[0];
    float s = f * g;
    float mx = s;
    for (int off = 32; off; off >>= 1) mx = fmaxf(mx, __shfl_xor(mx, off));
    float e = expf(s - mx);
    float sum = e;
    for (int off = 32; off; off >>= 1) sum += __shfl_xor(sum, off);
    beta[b * T_ + t] = e / sum;
}

// ---------------------------------------------------------------------------
// out[b,p,n] = b_out[p] + sum_t beta[b,t]*hs1[b,t,n]*W_out[t,p]
// ---------------------------------------------------------------------------
__global__ __launch_bounds__(256) void att_out_kernel(
    const float* __restrict__ hs1, const float* __restrict__ beta,
    const float* __restrict__ Wout, const float* __restrict__ bout,
    float* __restrict__ out) {
    __shared__ float bs[T_];
    __shared__ float ws[T_][P_];
    const int b = blockIdx.x;
    const int tid = threadIdx.x;
    if (tid < T_) bs[tid] = beta[b * T_ + tid];
    for (int i = tid; i < T_ * P_; i += 256) ws[i / P_][i % P_] = Wout[i];
    __syncthreads();
    for (int nn = 0; nn < 2; ++nn) {
        const int n = tid + nn * 256;
        float acc[P_];
#pragma unroll
        for (int p = 0; p < P_; ++p) acc[p] = bout[p];
        for (int t = 0; t < T_; ++t) {
            float v = bs[t] * hs1[((size_t)b * T_ + t) * N_ + n];
#pragma unroll
            for (int p = 0; p < P_; ++p) acc[p] += v * ws[t][p];
        }
#pragma unroll
        for (int p = 0; p < P_; ++p) out[((size_t)b * P_ + p) * N_ + n] = acc[p];
    }
}

extern "C" void kernel_launch(void* const* d_in, const int* in_sizes, int n_in,
                              void* d_out, int out_size, void* d_ws, size_t ws_size,
                              hipStream_t stream) {
    const float* x = (const float*)d_in[0];
    const float* L = (const float*)d_in[1];
    const float* W1 = (const float*)d_in[2];
    const float* b1 = (const float*)d_in[3];
    const float* W2 = (const float*)d_in[4];
    const float* b2 = (const float*)d_in[5];
    const float* aw1 = (const float*)d_in[6];
    const float* aw2 = (const float*)d_in[7];
    const float* aw3 = (const float*)d_in[8];
    const float* ab1 = (const float*)d_in[9];
    const float* ab2 = (const float*)d_in[10];
    const float* ab3 = (const float*)d_in[11];
    const float* Wout = (const float*)d_in[12];
    const float* bout = (const float*)d_in[13];
    float* out = (float*)d_out;

    float* ws = (float*)d_ws;
    float* Lx = ws;                      // B*T*N
    float* hs1 = Lx + B_ * T_ * N_;      // B*T*N
    float* hb0 = hs1 + B_ * T_ * N_;     // B*N*H
    float* hb1 = hb0 + (size_t)B_ * NH;  // B*N*H
    float* rh = hb1 + (size_t)B_ * NH;   // B*N*H
    float* u = rh + (size_t)B_ * NH;     // B*N*H
    float* beta = u + (size_t)B_ * NH;   // B*T
    (void)in_sizes; (void)n_in; (void)out_size; (void)ws_size;

    hipMemsetAsync(hb0, 0, (size_t)B_ * NH * sizeof(float), stream);
    lx_kernel<<<256, 512, 0, stream>>>(x, L, Lx);

    for (int t = 0; t < T_; ++t) {
        float* hp = (t & 1) ? hb1 : hb0;
        float* hn = (t & 1) ? hb0 : hb1;
        gc1_kernel<<<512, 512, 0, stream>>>(L, hp, Lx, W1, b1, rh, u, t);
        gc2_kernel<<<512, 512, 0, stream>>>(L, hp, rh, u, Lx, W2, b2, aw1, ab1,
                                            hn, hs1, t);
    }
    att_beta_kernel<<<16, 64, 0, stream>>>(hs1, aw2, aw3, ab2, ab3, beta);
    att_out_kernel<<<16, 256, 0, stream>>>(hs1, beta, Wout, bout, out);
}

// Round 6
// 4447.894 us; speedup vs baseline: 12.1193x; 5.0486x over previous
//
#include <hip/hip_runtime.h>
#include <math.h>

#define B_ 16
#define T_ 64
#define N_ 512
#define H_ 128
#define P_ 12
#define NH 65536  // N_*H_

// ---------------------------------------------------------------------------
// Lx[b,t,m] = sum_n L[m,n] * x[b,t,n]   (L symmetric)
// ---------------------------------------------------------------------------
__global__ __launch_bounds__(512) void lx_kernel(const float* __restrict__ x,
                                                 const float* __restrict__ L,
                                                 float* __restrict__ Lx) {
    __shared__ __align__(16) float xs[4][N_];
    const int r0 = blockIdx.x * 4;
    const int tid = threadIdx.x;
    for (int j = 0; j < 4; ++j)
        xs[j][tid] = x[(size_t)(r0 + j) * N_ + tid];
    __syncthreads();
    float a0 = 0.f, a1 = 0.f, a2 = 0.f, a3 = 0.f;
    const int m = tid;
#pragma unroll 8
    for (int n = 0; n < N_; ++n) {
        float lv = L[(size_t)n * N_ + m];
        a0 += xs[0][n] * lv;
        a1 += xs[1][n] * lv;
        a2 += xs[2][n] * lv;
        a3 += xs[3][n] * lv;
    }
    Lx[(size_t)(r0 + 0) * N_ + m] = a0;
    Lx[(size_t)(r0 + 1) * N_ + m] = a1;
    Lx[(size_t)(r0 + 2) * N_ + m] = a2;
    Lx[(size_t)(r0 + 3) * N_ + m] = a3;
}

// ===========================================================================
// gc1 (R2-verified structure, 4316 us baseline) with exactly two diffs:
//  (1) Lt pitch 36 -> 33: transposed staging stores become conflict-free
//      (bank = (4t+j+lm) mod 32, bijective over lane -> 2 lanes/bank = free).
//  (2) block decode swapped: b = blockIdx&15 -> XCD = blockIdx%8 = b%8, so
//      each XCD's L2 holds only 2 H-panels (~1.7 MB) instead of all 16 (>4MB).
// NOTE: plain __launch_bounds__(512) — (512,4) forced 64 VGPRs + full spill.
// NOTE: W1 MUST be staged via LDS; global-streamed W thrashed L2 (R3/R4).
// NOTE: keep 256-block grid; 512-block variants regressed (R3/R4/R5).
// ===========================================================================
__global__ __launch_bounds__(512) void gc1_kernel(
    const float* __restrict__ L, const float* __restrict__ Hprev,
    const float* __restrict__ Lx, const float* __restrict__ W1,
    const float* __restrict__ b1, float* __restrict__ rh,
    float* __restrict__ u, int t) {
    union Sm {
        struct { float Ht[2][64][128]; float Lt[2][64][33]; } p;  // 82432 B
        float Wt[32][260];                                        // 33280 B
    };
    __shared__ __align__(16) Sm sm;
    __shared__ __align__(16) float Zs[4][32][128];                // 65536 B

    const int tid = threadIdx.x;
    const int b = blockIdx.x & 15;        // diff (2): XCD-locality decode
    const int m0 = (blockIdx.x >> 4) * 32;
    const int g = tid >> 7;        // k-group 0..3
    const int gt = tid & 127;
    const int tx = gt & 31, ty = gt >> 5;
    const int c0 = tx * 4;

    const float* __restrict__ Hb = Hprev + (size_t)b * NH;

    const int hrow = tid >> 5, hcol = (tid & 31) * 4;  // H: 64 rows x 128 cols
    const int lm = tid >> 4, lk0 = (tid & 15) * 4;     // L: 32 m x 64 k (transposed store)

    // ---- stage chunk 0
    {
#pragma unroll
        for (int jj = 0; jj < 4; ++jj)
            *(float4*)&sm.p.Ht[0][hrow + 16 * jj][hcol] =
                *(const float4*)&Hb[(size_t)(hrow + 16 * jj) * H_ + hcol];
        float4 lv = *(const float4*)&L[(size_t)(m0 + lm) * N_ + lk0];
        sm.p.Lt[0][lk0 + 0][lm] = lv.x;
        sm.p.Lt[0][lk0 + 1][lm] = lv.y;
        sm.p.Lt[0][lk0 + 2][lm] = lv.z;
        sm.p.Lt[0][lk0 + 3][lm] = lv.w;
    }
    __syncthreads();

    float acc[8][4] = {};

    for (int kc = 0; kc < 8; ++kc) {
        const int bi = kc & 1, bj = bi ^ 1;
        float4 h0, h1, h2, h3, lv;
        if (kc < 7) {
            const size_t kb2 = (size_t)(kc + 1) * 64;
            h0 = *(const float4*)&Hb[(kb2 + hrow) * H_ + hcol];
            h1 = *(const float4*)&Hb[(kb2 + hrow + 16) * H_ + hcol];
            h2 = *(const float4*)&Hb[(kb2 + hrow + 32) * H_ + hcol];
            h3 = *(const float4*)&Hb[(kb2 + hrow + 48) * H_ + hcol];
            lv = *(const float4*)&L[(size_t)(m0 + lm) * N_ + kb2 + lk0];
        }
#pragma unroll
        for (int kk = 0; kk < 16; ++kk) {
            const int k = g * 16 + kk;
            const float4 la = *(const float4*)&sm.p.Lt[bi][k][ty * 8];
            const float4 lb = *(const float4*)&sm.p.Lt[bi][k][ty * 8 + 4];
            const float4 hv = *(const float4*)&sm.p.Ht[bi][k][c0];
#define FMA_ROW(r, s)                                                   \
            acc[r][0] += (s) * hv.x; acc[r][1] += (s) * hv.y;           \
            acc[r][2] += (s) * hv.z; acc[r][3] += (s) * hv.w;
            FMA_ROW(0, la.x) FMA_ROW(1, la.y) FMA_ROW(2, la.z) FMA_ROW(3, la.w)
            FMA_ROW(4, lb.x) FMA_ROW(5, lb.y) FMA_ROW(6, lb.z) FMA_ROW(7, lb.w)
#undef FMA_ROW
        }
        if (kc < 7) {
            *(float4*)&sm.p.Ht[bj][hrow][hcol] = h0;
            *(float4*)&sm.p.Ht[bj][hrow + 16][hcol] = h1;
            *(float4*)&sm.p.Ht[bj][hrow + 32][hcol] = h2;
            *(float4*)&sm.p.Ht[bj][hrow + 48][hcol] = h3;
            sm.p.Lt[bj][lk0 + 0][lm] = lv.x;
            sm.p.Lt[bj][lk0 + 1][lm] = lv.y;
            sm.p.Lt[bj][lk0 + 2][lm] = lv.z;
            sm.p.Lt[bj][lk0 + 3][lm] = lv.w;
        }
        __syncthreads();
    }

    // write k-split partials
#pragma unroll
    for (int r = 0; r < 8; ++r)
        *(float4*)&Zs[g][ty * 8 + r][c0] =
            make_float4(acc[r][0], acc[r][1], acc[r][2], acc[r][3]);
    __syncthreads();

    // reduce 4 partials into Zs[0]
    for (int j = tid; j < 1024; j += 512) {
        const int m = j >> 5, cc = (j & 31) * 4;
        float4 z0 = *(const float4*)&Zs[0][m][cc];
        float4 z1 = *(const float4*)&Zs[1][m][cc];
        float4 z2 = *(const float4*)&Zs[2][m][cc];
        float4 z3 = *(const float4*)&Zs[3][m][cc];
        *(float4*)&Zs[0][m][cc] = make_float4(z0.x + z1.x + z2.x + z3.x,
                                              z0.y + z1.y + z2.y + z3.y,
                                              z0.z + z1.z + z2.z + z3.z,
                                              z0.w + z1.w + z2.w + z3.w);
    }
    __syncthreads();

    // ---- phase 2: out = Z @ W1[1:,:]  (W staged in LDS, 32-ch chunks)
    const int to = tid & 63, tm = tid >> 6;
    const int o0 = to * 4;
    float a2[4][4] = {};
    const int wr = tid >> 4, wc = (tid & 15) * 16;

    for (int c4 = 0; c4 < 4; ++c4) {
#pragma unroll
        for (int jj = 0; jj < 4; ++jj)
            *(float4*)&sm.Wt[wr][wc + 4 * jj] =
                *(const float4*)&W1[(size_t)(1 + c4 * 32 + wr) * 256 + wc + 4 * jj];
        __syncthreads();
#pragma unroll
        for (int ch4 = 0; ch4 < 8; ++ch4) {
            const float4 w0v = *(const float4*)&sm.Wt[ch4 * 4 + 0][o0];
            const float4 w1v = *(const float4*)&sm.Wt[ch4 * 4 + 1][o0];
            const float4 w2v = *(const float4*)&sm.Wt[ch4 * 4 + 2][o0];
            const float4 w3v = *(const float4*)&sm.Wt[ch4 * 4 + 3][o0];
#pragma unroll
            for (int i = 0; i < 4; ++i) {
                const float4 zv = *(const float4*)&Zs[0][tm + 8 * i][c4 * 32 + ch4 * 4];
                a2[i][0] += zv.x * w0v.x + zv.y * w1v.x + zv.z * w2v.x + zv.w * w3v.x;
                a2[i][1] += zv.x * w0v.y + zv.y * w1v.y + zv.z * w2v.y + zv.w * w3v.y;
                a2[i][2] += zv.x * w0v.z + zv.y * w1v.z + zv.z * w2v.z + zv.w * w3v.z;
                a2[i][3] += zv.x * w0v.w + zv.y * w1v.w + zv.z * w2v.w + zv.w * w3v.w;
            }
        }
        __syncthreads();
    }

    // ---- epilogue (verified)
    const float4 w0r = *(const float4*)&W1[o0];   // row 0 (x channel)
    const float4 bbv = *(const float4*)&b1[o0];
    const float* __restrict__ LxRow = Lx + ((size_t)b * T_ + t) * N_ + m0;
    float* __restrict__ rhB = rh + (size_t)b * NH;
    float* __restrict__ uB = u + (size_t)b * NH;
    const bool isR = (m0 < 256);
#pragma unroll
    for (int i = 0; i < 4; ++i) {
        const int mi = tm + 8 * i;
        const float lx = LxRow[mi];
        float v0 = a2[i][0] + lx * w0r.x + bbv.x;
        float v1 = a2[i][1] + lx * w0r.y + bbv.y;
        float v2 = a2[i][2] + lx * w0r.z + bbv.z;
        float v3 = a2[i][3] + lx * w0r.w + bbv.w;
        float s0 = 1.f / (1.f + expf(-v0));
        float s1 = 1.f / (1.f + expf(-v1));
        float s2 = 1.f / (1.f + expf(-v2));
        float s3 = 1.f / (1.f + expf(-v3));
        const int fl = (m0 + mi) * 256 + o0;
        if (isR) {
            float4 hv = *(const float4*)&Hb[fl];
            *(float4*)&rhB[fl] = make_float4(s0 * hv.x, s1 * hv.y, s2 * hv.z, s3 * hv.w);
        } else {
            *(float4*)&uB[fl - NH] = make_float4(s0, s1, s2, s3);
        }
    }
}

// ===========================================================================
// gc2 (R2-verified structure) with the same two diffs as gc1.
// ===========================================================================
__global__ __launch_bounds__(512) void gc2_kernel(
    const float* __restrict__ L, const float* __restrict__ Hprev,
    const float* __restrict__ rh, const float* __restrict__ u,
    const float* __restrict__ Lx, const float* __restrict__ W2,
    const float* __restrict__ b2, const float* __restrict__ aw1,
    const float* __restrict__ ab1, float* __restrict__ Hnew,
    float* __restrict__ hs1, int t) {
    union Sm {
        struct { float Ht[2][64][128]; float Lt[2][64][33]; } p;  // 82432 B
        float Wt[32][132];                                        // 16896 B
    };
    __shared__ __align__(16) Sm sm;
    __shared__ __align__(16) float Zs[4][32][128];                // 65536 B
    __shared__ __align__(16) float red[32][32];                   //  4096 B

    const int tid = threadIdx.x;
    const int b = blockIdx.x & 15;        // diff (2)
    const int m0 = (blockIdx.x >> 4) * 32;
    const int g = tid >> 7;
    const int gt = tid & 127;
    const int tx = gt & 31, ty = gt >> 5;
    const int c0 = tx * 4;

    const float* __restrict__ Rb = rh + (size_t)b * NH;
    const float* __restrict__ Hb = Hprev + (size_t)b * NH;
    const float* __restrict__ Ub = u + (size_t)b * NH;

    const int hrow = tid >> 5, hcol = (tid & 31) * 4;
    const int lm = tid >> 4, lk0 = (tid & 15) * 4;

    {
#pragma unroll
        for (int jj = 0; jj < 4; ++jj)
            *(float4*)&sm.p.Ht[0][hrow + 16 * jj][hcol] =
                *(const float4*)&Rb[(size_t)(hrow + 16 * jj) * H_ + hcol];
        float4 lv = *(const float4*)&L[(size_t)(m0 + lm) * N_ + lk0];
        sm.p.Lt[0][lk0 + 0][lm] = lv.x;
        sm.p.Lt[0][lk0 + 1][lm] = lv.y;
        sm.p.Lt[0][lk0 + 2][lm] = lv.z;
        sm.p.Lt[0][lk0 + 3][lm] = lv.w;
    }
    __syncthreads();

    float acc[8][4] = {};

    for (int kc = 0; kc < 8; ++kc) {
        const int bi = kc & 1, bj = bi ^ 1;
        float4 h0, h1, h2, h3, lv;
        if (kc < 7) {
            const size_t kb2 = (size_t)(kc + 1) * 64;
            h0 = *(const float4*)&Rb[(kb2 + hrow) * H_ + hcol];
            h1 = *(const float4*)&Rb[(kb2 + hrow + 16) * H_ + hcol];
            h2 = *(const float4*)&Rb[(kb2 + hrow + 32) * H_ + hcol];
            h3 = *(const float4*)&Rb[(kb2 + hrow + 48) * H_ + hcol];
            lv = *(const float4*)&L[(size_t)(m0 + lm) * N_ + kb2 + lk0];
        }
#pragma unroll
        for (int kk = 0; kk < 16; ++kk) {
            const int k = g * 16 + kk;
            const float4 la = *(const float4*)&sm.p.Lt[bi][k][ty * 8];
            const float4 lb = *(const float4*)&sm.p.Lt[bi][k][ty * 8 + 4];
            const float4 hv = *(const float4*)&sm.p.Ht[bi][k][c0];
#define FMA_ROW(r, s)                                                   \
            acc[r][0] += (s) * hv.x; acc[r][1] += (s) * hv.y;           \
            acc[r][2] += (s) * hv.z; acc[r][3] += (s) * hv.w;
            FMA_ROW(0, la.x) FMA_ROW(1, la.y) FMA_ROW(2, la.z) FMA_ROW(3, la.w)
            FMA_ROW(4, lb.x) FMA_ROW(5, lb.y) FMA_ROW(6, lb.z) FMA_ROW(7, lb.w)
#undef FMA_ROW
        }
        if (kc < 7) {
            *(float4*)&sm.p.Ht[bj][hrow][hcol] = h0;
            *(float4*)&sm.p.Ht[bj][hrow + 16][hcol] = h1;
            *(float4*)&sm.p.Ht[bj][hrow + 32][hcol] = h2;
            *(float4*)&sm.p.Ht[bj][hrow + 48][hcol] = h3;
            sm.p.Lt[bj][lk0 + 0][lm] = lv.x;
            sm.p.Lt[bj][lk0 + 1][lm] = lv.y;
            sm.p.Lt[bj][lk0 + 2][lm] = lv.z;
            sm.p.Lt[bj][lk0 + 3][lm] = lv.w;
        }
        __syncthreads();
    }

#pragma unroll
    for (int r = 0; r < 8; ++r)
        *(float4*)&Zs[g][ty * 8 + r][c0] =
            make_float4(acc[r][0], acc[r][1], acc[r][2], acc[r][3]);
    __syncthreads();

    for (int j = tid; j < 1024; j += 512) {
        const int m = j >> 5, cc = (j & 31) * 4;
        float4 z0 = *(const float4*)&Zs[0][m][cc];
        float4 z1 = *(const float4*)&Zs[1][m][cc];
        float4 z2 = *(const float4*)&Zs[2][m][cc];
        float4 z3 = *(const float4*)&Zs[3][m][cc];
        *(float4*)&Zs[0][m][cc] = make_float4(z0.x + z1.x + z2.x + z3.x,
                                              z0.y + z1.y + z2.y + z3.y,
                                              z0.z + z1.z + z2.z + z3.z,
                                              z0.w + z1.w + z2.w + z3.w);
    }
    __syncthreads();

    // ---- phase 2: o range 128
    const int to = tid & 31, tm = tid >> 5;  // 16 m-groups, 2 m each
    const int o0 = to * 4;
    float a2[2][4] = {};
    const int wr = tid >> 4, wc = (tid & 15) * 8;

    for (int c4 = 0; c4 < 4; ++c4) {
#pragma unroll
        for (int jj = 0; jj < 2; ++jj)
            *(float4*)&sm.Wt[wr][wc + 4 * jj] =
                *(const float4*)&W2[(size_t)(1 + c4 * 32 + wr) * H_ + wc + 4 * jj];
        __syncthreads();
#pragma unroll
        for (int ch4 = 0; ch4 < 8; ++ch4) {
            const float4 w0v = *(const float4*)&sm.Wt[ch4 * 4 + 0][o0];
            const float4 w1v = *(const float4*)&sm.Wt[ch4 * 4 + 1][o0];
            const float4 w2v = *(const float4*)&sm.Wt[ch4 * 4 + 2][o0];
            const float4 w3v = *(const float4*)&sm.Wt[ch4 * 4 + 3][o0];
#pragma unroll
            for (int i = 0; i < 2; ++i) {
                const float4 zv = *(const float4*)&Zs[0][tm + 16 * i][c4 * 32 + ch4 * 4];
                a2[i][0] += zv.x * w0v.x + zv.y * w1v.x + zv.z * w2v.x + zv.w * w3v.x;
                a2[i][1] += zv.x * w0v.y + zv.y * w1v.y + zv.z * w2v.y + zv.w * w3v.y;
                a2[i][2] += zv.x * w0v.z + zv.y * w1v.z + zv.z * w2v.z + zv.w * w3v.z;
                a2[i][3] += zv.x * w0v.w + zv.y * w1v.w + zv.z * w2v.w + zv.w * w3v.w;
            }
        }
        __syncthreads();
    }

    // ---- epilogue (verified)
    const float4 w0r = *(const float4*)&W2[o0];
    const float4 bbv = *(const float4*)&b2[o0];
    const float4 awv = *(const float4*)&aw1[o0];
    const float* __restrict__ LxRow = Lx + ((size_t)b * T_ + t) * N_ + m0;
    float* __restrict__ HnB = Hnew + (size_t)b * NH;
#pragma unroll
    for (int i = 0; i < 2; ++i) {
        const int mi = tm + 16 * i;
        const float lx = LxRow[mi];
        float c0e = tanhf(a2[i][0] + lx * w0r.x + bbv.x);
        float c1e = tanhf(a2[i][1] + lx * w0r.y + bbv.y);
        float c2e = tanhf(a2[i][2] + lx * w0r.z + bbv.z);
        float c3e = tanhf(a2[i][3] + lx * w0r.w + bbv.w);
        const int fl = (m0 + mi) * H_ + o0;
        float4 uv = *(const float4*)&Ub[fl];
        float4 hp = *(const float4*)&Hb[fl];
        float h0 = uv.x * hp.x + (1.f - uv.x) * c0e;
        float h1 = uv.y * hp.y + (1.f - uv.y) * c1e;
        float h2 = uv.z * hp.z + (1.f - uv.z) * c2e;
        float h3 = uv.w * hp.w + (1.f - uv.w) * c3e;
        *(float4*)&HnB[fl] = make_float4(h0, h1, h2, h3);
        red[mi][to] = h0 * awv.x + h1 * awv.y + h2 * awv.z + h3 * awv.w;
    }
    __syncthreads();
    if (tid < 32) {
        float s = 0.f;
#pragma unroll
        for (int k2 = 0; k2 < 32; ++k2) s += red[tid][k2];
        hs1[((size_t)b * T_ + t) * N_ + m0 + tid] = s + ab1[0];
    }
}

// ---------------------------------------------------------------------------
// beta[b,t] = softmax_t( (hs1@aw2+ab2) * (hs1@aw3+ab3) )
// ---------------------------------------------------------------------------
__global__ __launch_bounds__(64) void att_beta_kernel(
    const float* __restrict__ hs1, const float* __restrict__ aw2,
    const float* __restrict__ aw3, const float* __restrict__ ab2,
    const float* __restrict__ ab3, float* __restrict__ beta) {
    const int b = blockIdx.x;
    const int t = threadIdx.x;
    const float* __restrict__ row = hs1 + ((size_t)b * T_ + t) * N_;
    float f = 0.f, g = 0.f;
    for (int n = 0; n < N_; n += 4) {
        float4 hv = *(const float4*)&row[n];
        float4 w2v = *(const float4*)&aw2[n];
        float4 w3v = *(const float4*)&aw3[n];
        f += hv.x * w2v.x + hv.y * w2v.y + hv.z * w2v.z + hv.w * w2v.w;
        g += hv.x * w3v.x + hv.y * w3v.y + hv.z * w3v.z + hv.w * w3v.w;
    }
    f += ab2[0];
    g += ab3[0];
    float s = f * g;
    float mx = s;
    for (int off = 32; off; off >>= 1) mx = fmaxf(mx, __shfl_xor(mx, off));
    float e = expf(s - mx);
    float sum = e;
    for (int off = 32; off; off >>= 1) sum += __shfl_xor(sum, off);
    beta[b * T_ + t] = e / sum;
}

// ---------------------------------------------------------------------------
// out[b,p,n] = b_out[p] + sum_t beta[b,t]*hs1[b,t,n]*W_out[t,p]
// ---------------------------------------------------------------------------
__global__ __launch_bounds__(256) void att_out_kernel(
    const float* __restrict__ hs1, const float* __restrict__ beta,
    const float* __restrict__ Wout, const float* __restrict__ bout,
    float* __restrict__ out) {
    __shared__ float bs[T_];
    __shared__ float ws[T_][P_];
    const int b = blockIdx.x;
    const int tid = threadIdx.x;
    if (tid < T_) bs[tid] = beta[b * T_ + tid];
    for (int i = tid; i < T_ * P_; i += 256) ws[i / P_][i % P_] = Wout[i];
    __syncthreads();
    for (int nn = 0; nn < 2; ++nn) {
        const int n = tid + nn * 256;
        float acc[P_];
#pragma unroll
        for (int p = 0; p < P_; ++p) acc[p] = bout[p];
        for (int t = 0; t < T_; ++t) {
            float v = bs[t] * hs1[((size_t)b * T_ + t) * N_ + n];
#pragma unroll
            for (int p = 0; p < P_; ++p) acc[p] += v * ws[t][p];
        }
#pragma unroll
        for (int p = 0; p < P_; ++p) out[((size_t)b * P_ + p) * N_ + n] = acc[p];
    }
}

extern "C" void kernel_launch(void* const* d_in, const int* in_sizes, int n_in,
                              void* d_out, int out_size, void* d_ws, size_t ws_size,
                              hipStream_t stream) {
    const float* x = (const float*)d_in[0];
    const float* L = (const float*)d_in[1];
    const float* W1 = (const float*)d_in[2];
    const float* b1 = (const float*)d_in[3];
    const float* W2 = (const float*)d_in[4];
    const float* b2 = (const float*)d_in[5];
    const float* aw1 = (const float*)d_in[6];
    const float* aw2 = (const float*)d_in[7];
    const float* aw3 = (const float*)d_in[8];
    const float* ab1 = (const float*)d_in[9];
    const float* ab2 = (const float*)d_in[10];
    const float* ab3 = (const float*)d_in[11];
    const float* Wout = (const float*)d_in[12];
    const float* bout = (const float*)d_in[13];
    float* out = (float*)d_out;

    float* ws = (float*)d_ws;
    float* Lx = ws;                      // B*T*N
    float* hs1 = Lx + B_ * T_ * N_;      // B*T*N
    float* hb0 = hs1 + B_ * T_ * N_;     // B*N*H
    float* hb1 = hb0 + (size_t)B_ * NH;  // B*N*H
    float* rh = hb1 + (size_t)B_ * NH;   // B*N*H
    float* u = rh + (size_t)B_ * NH;     // B*N*H
    float* beta = u + (size_t)B_ * NH;   // B*T
    (void)in_sizes; (void)n_in; (void)out_size; (void)ws_size;

    hipMemsetAsync(hb0, 0, (size_t)B_ * NH * sizeof(float), stream);
    lx_kernel<<<256, 512, 0, stream>>>(x, L, Lx);

    for (int t = 0; t < T_; ++t) {
        float* hp = (t & 1) ? hb1 : hb0;
        float* hn = (t & 1) ? hb0 : hb1;
        gc1_kernel<<<256, 512, 0, stream>>>(L, hp, Lx, W1, b1, rh, u, t);
        gc2_kernel<<<256, 512, 0, stream>>>(L, hp, rh, u, Lx, W2, b2, aw1, ab1,
                                            hn, hs1, t);
    }
    att_beta_kernel<<<16, 64, 0, stream>>>(hs1, aw2, aw3, ab2, ab3, beta);
    att_out_kernel<<<16, 256, 0, stream>>>(hs1, beta, Wout, bout, out);
}

// Round 7
// 4007.905 us; speedup vs baseline: 13.4498x; 1.1098x over previous
//
#include <hip/hip_runtime.h>
#include <math.h>

#define B_ 16
#define T_ 64
#define N_ 512
#define H_ 128
#define P_ 12
#define NH 65536  // N_*H_

// ---------------------------------------------------------------------------
// Lx[b,t,m] = sum_n L[m,n] * x[b,t,n]   (L symmetric)
// ---------------------------------------------------------------------------
__global__ __launch_bounds__(512) void lx_kernel(const float* __restrict__ x,
                                                 const float* __restrict__ L,
                                                 float* __restrict__ Lx) {
    __shared__ __align__(16) float xs[4][N_];
    const int r0 = blockIdx.x * 4;
    const int tid = threadIdx.x;
    for (int j = 0; j < 4; ++j)
        xs[j][tid] = x[(size_t)(r0 + j) * N_ + tid];
    __syncthreads();
    float a0 = 0.f, a1 = 0.f, a2 = 0.f, a3 = 0.f;
    const int m = tid;
#pragma unroll 8
    for (int n = 0; n < N_; ++n) {
        float lv = L[(size_t)n * N_ + m];
        a0 += xs[0][n] * lv;
        a1 += xs[1][n] * lv;
        a2 += xs[2][n] * lv;
        a3 += xs[3][n] * lv;
    }
    Lx[(size_t)(r0 + 0) * N_ + m] = a0;
    Lx[(size_t)(r0 + 1) * N_ + m] = a1;
    Lx[(size_t)(r0 + 2) * N_ + m] = a2;
    Lx[(size_t)(r0 + 3) * N_ + m] = a3;
}

// ===========================================================================
// gc1: Z = L@Hprev ; ru = sigmoid(Z@W1[1:] + Lx*W1[0] + b1)
//      flat<65536 -> rh = ru*h ; else u = ru
// grid 256 = mtile(16 of 32 rows) x b(16), b = blockIdx&15 (XCD locality, R6).
// LDS 65792 B -> 2 blocks/CU (the R6 bottleneck was 148 KB -> 1 block/CU,
// 2 waves/SIMD, ~32 us of exposed barrier/staging stall at VALUBusy 31%).
// NOTE: plain __launch_bounds__(512) — (512,4) forced 64 VGPRs + full spill (R3).
// NOTE: W1 MUST be staged via LDS; global-streamed W thrashed L2 (R3/R4).
// ===========================================================================
__global__ __launch_bounds__(512) void gc1_kernel(
    const float* __restrict__ L, const float* __restrict__ Hprev,
    const float* __restrict__ Lx, const float* __restrict__ W1,
    const float* __restrict__ b1, float* __restrict__ rh,
    float* __restrict__ u, int t) {
    __shared__ __align__(16) float Ht[2][32][H_];   // 32768 B
    union LW {
        float Lt[2][32][33];   // 8448 B, transposed [k][m], pitch 33 (conflict-free)
        float Wt[16][260];     // 16640 B, phase-2 W chunk
    };
    __shared__ __align__(16) LW sm;
    __shared__ __align__(16) float Zb[32][H_];      // 16384 B   -> total 65792 B

    const int tid = threadIdx.x;
    const int b = blockIdx.x & 15;         // XCD-locality decode (verified R6)
    const int m0 = (blockIdx.x >> 4) * 32;
    const float* __restrict__ Hb = Hprev + (size_t)b * NH;

    // staging indices: H rows dense (each b128 store = 1024 B dense, no stride)
    const int hrow = tid >> 5, hcol = (tid & 31) * 4;  // 16 rows x 128 cols x2
    const int lm = tid >> 4, lk0 = (tid & 15) * 2;     // L: 32 m x 32 k (transposed)

    // ---- stage chunk 0
    {
        *(float4*)&Ht[0][hrow][hcol] = *(const float4*)&Hb[(size_t)hrow * H_ + hcol];
        *(float4*)&Ht[0][hrow + 16][hcol] =
            *(const float4*)&Hb[(size_t)(hrow + 16) * H_ + hcol];
        float2 lv = *(const float2*)&L[(size_t)(m0 + lm) * N_ + lk0];
        sm.Lt[0][lk0 + 0][lm] = lv.x;
        sm.Lt[0][lk0 + 1][lm] = lv.y;
    }
    __syncthreads();

    // ---- phase 1: k-split x2, 4m x 4c per thread
    const int g = tid >> 8;          // k-group 0/1 (wave-uniform)
    const int gt = tid & 255;
    const int tx = gt & 31, ty = gt >> 5;   // tx: c-group, ty: m-group 0..7
    const int c0 = tx * 4, mrow = ty * 4;

    float acc[4][4] = {};

    for (int kc = 0; kc < 16; ++kc) {
        const int bi = kc & 1, bj = bi ^ 1;
        float4 p0, p1;
        float2 pl;
        if (kc < 15) {
            const size_t kb = (size_t)(kc + 1) * 32;
            p0 = *(const float4*)&Hb[(kb + hrow) * H_ + hcol];
            p1 = *(const float4*)&Hb[(kb + hrow + 16) * H_ + hcol];
            pl = *(const float2*)&L[(size_t)(m0 + lm) * N_ + kb + lk0];
        }
#pragma unroll
        for (int kk = 0; kk < 16; ++kk) {
            const int k = g * 16 + kk;
            const float4 la = *(const float4*)&sm.Lt[bi][k][mrow];  // 2-addr bcast
            const float4 hv = *(const float4*)&Ht[bi][k][c0];       // dense
            acc[0][0] += la.x * hv.x; acc[0][1] += la.x * hv.y;
            acc[0][2] += la.x * hv.z; acc[0][3] += la.x * hv.w;
            acc[1][0] += la.y * hv.x; acc[1][1] += la.y * hv.y;
            acc[1][2] += la.y * hv.z; acc[1][3] += la.y * hv.w;
            acc[2][0] += la.z * hv.x; acc[2][1] += la.z * hv.y;
            acc[2][2] += la.z * hv.z; acc[2][3] += la.z * hv.w;
            acc[3][0] += la.w * hv.x; acc[3][1] += la.w * hv.y;
            acc[3][2] += la.w * hv.z; acc[3][3] += la.w * hv.w;
        }
        if (kc < 15) {
            *(float4*)&Ht[bj][hrow][hcol] = p0;
            *(float4*)&Ht[bj][hrow + 16][hcol] = p1;
            sm.Lt[bj][lk0 + 0][lm] = pl.x;
            sm.Lt[bj][lk0 + 1][lm] = pl.y;
        }
        __syncthreads();
    }

    // ---- merge k-split partials through Zb (register-side add)
    if (g == 1) {
#pragma unroll
        for (int i = 0; i < 4; ++i)
            *(float4*)&Zb[mrow + i][c0] =
                make_float4(acc[i][0], acc[i][1], acc[i][2], acc[i][3]);
    }
    __syncthreads();
    if (g == 0) {
#pragma unroll
        for (int i = 0; i < 4; ++i) {
            float4 z = *(const float4*)&Zb[mrow + i][c0];
            *(float4*)&Zb[mrow + i][c0] = make_float4(
                acc[i][0] + z.x, acc[i][1] + z.y, acc[i][2] + z.z, acc[i][3] + z.w);
        }
    }
    __syncthreads();

    // ---- phase 2: out = Z @ W1[1:,:]  (W in LDS, 8 chunks of 16 ch)
    const int to = tid & 63, tm = tid >> 6;  // o0 in [0,256), 8 m-groups of 4
    const int o0 = to * 4;
    float a2[4][4] = {};
    const int wr = tid >> 5, wc = (tid & 31) * 4;

    for (int ck = 0; ck < 8; ++ck) {
        *(float4*)&sm.Wt[wr][wc] =
            *(const float4*)&W1[(size_t)(1 + ck * 16 + wr) * 256 + wc];
        *(float4*)&sm.Wt[wr][wc + 128] =
            *(const float4*)&W1[(size_t)(1 + ck * 16 + wr) * 256 + wc + 128];
        __syncthreads();
#pragma unroll
        for (int ch4 = 0; ch4 < 4; ++ch4) {
            const float4 w0v = *(const float4*)&sm.Wt[ch4 * 4 + 0][o0];
            const float4 w1v = *(const float4*)&sm.Wt[ch4 * 4 + 1][o0];
            const float4 w2v = *(const float4*)&sm.Wt[ch4 * 4 + 2][o0];
            const float4 w3v = *(const float4*)&sm.Wt[ch4 * 4 + 3][o0];
            const int cc = ck * 16 + ch4 * 4;
#pragma unroll
            for (int i = 0; i < 4; ++i) {
                const float4 zv = *(const float4*)&Zb[tm + 8 * i][cc];
                a2[i][0] += zv.x * w0v.x + zv.y * w1v.x + zv.z * w2v.x + zv.w * w3v.x;
                a2[i][1] += zv.x * w0v.y + zv.y * w1v.y + zv.z * w2v.y + zv.w * w3v.y;
                a2[i][2] += zv.x * w0v.z + zv.y * w1v.z + zv.z * w2v.z + zv.w * w3v.z;
                a2[i][3] += zv.x * w0v.w + zv.y * w1v.w + zv.z * w2v.w + zv.w * w3v.w;
            }
        }
        __syncthreads();
    }

    // ---- epilogue (verified, verbatim layout: to=tid&63, tm=tid>>6, mi=tm+8i)
    const float4 w0r = *(const float4*)&W1[o0];   // row 0 (x channel)
    const float4 bbv = *(const float4*)&b1[o0];
    const float* __restrict__ LxRow = Lx + ((size_t)b * T_ + t) * N_ + m0;
    float* __restrict__ rhB = rh + (size_t)b * NH;
    float* __restrict__ uB = u + (size_t)b * NH;
    const bool isR = (m0 < 256);
#pragma unroll
    for (int i = 0; i < 4; ++i) {
        const int mi = tm + 8 * i;
        const float lx = LxRow[mi];
        float v0 = a2[i][0] + lx * w0r.x + bbv.x;
        float v1 = a2[i][1] + lx * w0r.y + bbv.y;
        float v2 = a2[i][2] + lx * w0r.z + bbv.z;
        float v3 = a2[i][3] + lx * w0r.w + bbv.w;
        float s0 = 1.f / (1.f + expf(-v0));
        float s1 = 1.f / (1.f + expf(-v1));
        float s2 = 1.f / (1.f + expf(-v2));
        float s3 = 1.f / (1.f + expf(-v3));
        const int fl = (m0 + mi) * 256 + o0;
        if (isR) {
            float4 hv = *(const float4*)&Hb[fl];
            *(float4*)&rhB[fl] = make_float4(s0 * hv.x, s1 * hv.y, s2 * hv.z, s3 * hv.w);
        } else {
            *(float4*)&uB[fl - NH] = make_float4(s0, s1, s2, s3);
        }
    }
}

// ===========================================================================
// gc2: Z = L@rh ; c = tanh(Z@W2[1:] + Lx*W2[0] + b2) ; hn = u*h + (1-u)*c
//      hs1[b,t,m] = hn[m,:] . att_w1 + att_b1
// Same structure as gc1; O=128. LDS 61696 B -> 2 blocks/CU.
// ===========================================================================
__global__ __launch_bounds__(512) void gc2_kernel(
    const float* __restrict__ L, const float* __restrict__ Hprev,
    const float* __restrict__ rh, const float* __restrict__ u,
    const float* __restrict__ Lx, const float* __restrict__ W2,
    const float* __restrict__ b2, const float* __restrict__ aw1,
    const float* __restrict__ ab1, float* __restrict__ Hnew,
    float* __restrict__ hs1, int t) {
    __shared__ __align__(16) float Ht[2][32][H_];   // 32768 B
    union LW {
        float Lt[2][32][33];   // 8448 B
        float Wt[16][132];     // 8448 B
    };
    __shared__ __align__(16) LW sm;
    __shared__ __align__(16) float Zb[32][H_];      // 16384 B
    __shared__ __align__(16) float red[32][32];     //  4096 B  -> total 61696 B

    const int tid = threadIdx.x;
    const int b = blockIdx.x & 15;
    const int m0 = (blockIdx.x >> 4) * 32;
    const float* __restrict__ Rb = rh + (size_t)b * NH;
    const float* __restrict__ Hb = Hprev + (size_t)b * NH;
    const float* __restrict__ Ub = u + (size_t)b * NH;

    const int hrow = tid >> 5, hcol = (tid & 31) * 4;
    const int lm = tid >> 4, lk0 = (tid & 15) * 2;

    {
        *(float4*)&Ht[0][hrow][hcol] = *(const float4*)&Rb[(size_t)hrow * H_ + hcol];
        *(float4*)&Ht[0][hrow + 16][hcol] =
            *(const float4*)&Rb[(size_t)(hrow + 16) * H_ + hcol];
        float2 lv = *(const float2*)&L[(size_t)(m0 + lm) * N_ + lk0];
        sm.Lt[0][lk0 + 0][lm] = lv.x;
        sm.Lt[0][lk0 + 1][lm] = lv.y;
    }
    __syncthreads();

    const int g = tid >> 8;
    const int gt = tid & 255;
    const int tx = gt & 31, ty = gt >> 5;
    const int c0 = tx * 4, mrow = ty * 4;

    float acc[4][4] = {};

    for (int kc = 0; kc < 16; ++kc) {
        const int bi = kc & 1, bj = bi ^ 1;
        float4 p0, p1;
        float2 pl;
        if (kc < 15) {
            const size_t kb = (size_t)(kc + 1) * 32;
            p0 = *(const float4*)&Rb[(kb + hrow) * H_ + hcol];
            p1 = *(const float4*)&Rb[(kb + hrow + 16) * H_ + hcol];
            pl = *(const float2*)&L[(size_t)(m0 + lm) * N_ + kb + lk0];
        }
#pragma unroll
        for (int kk = 0; kk < 16; ++kk) {
            const int k = g * 16 + kk;
            const float4 la = *(const float4*)&sm.Lt[bi][k][mrow];
            const float4 hv = *(const float4*)&Ht[bi][k][c0];
            acc[0][0] += la.x * hv.x; acc[0][1] += la.x * hv.y;
            acc[0][2] += la.x * hv.z; acc[0][3] += la.x * hv.w;
            acc[1][0] += la.y * hv.x; acc[1][1] += la.y * hv.y;
            acc[1][2] += la.y * hv.z; acc[1][3] += la.y * hv.w;
            acc[2][0] += la.z * hv.x; acc[2][1] += la.z * hv.y;
            acc[2][2] += la.z * hv.z; acc[2][3] += la.z * hv.w;
            acc[3][0] += la.w * hv.x; acc[3][1] += la.w * hv.y;
            acc[3][2] += la.w * hv.z; acc[3][3] += la.w * hv.w;
        }
        if (kc < 15) {
            *(float4*)&Ht[bj][hrow][hcol] = p0;
            *(float4*)&Ht[bj][hrow + 16][hcol] = p1;
            sm.Lt[bj][lk0 + 0][lm] = pl.x;
            sm.Lt[bj][lk0 + 1][lm] = pl.y;
        }
        __syncthreads();
    }

    if (g == 1) {
#pragma unroll
        for (int i = 0; i < 4; ++i)
            *(float4*)&Zb[mrow + i][c0] =
                make_float4(acc[i][0], acc[i][1], acc[i][2], acc[i][3]);
    }
    __syncthreads();
    if (g == 0) {
#pragma unroll
        for (int i = 0; i < 4; ++i) {
            float4 z = *(const float4*)&Zb[mrow + i][c0];
            *(float4*)&Zb[mrow + i][c0] = make_float4(
                acc[i][0] + z.x, acc[i][1] + z.y, acc[i][2] + z.z, acc[i][3] + z.w);
        }
    }
    __syncthreads();

    // ---- phase 2: O=128, 2m x 4o per thread, W2 in LDS (8 chunks of 16 ch)
    const int to = tid & 31, tm = tid >> 5;   // 16 m-groups of 2
    const int o0 = to * 4;
    float a2[2][4] = {};
    const int wr = tid >> 5, wc = (tid & 31) * 4;

    for (int ck = 0; ck < 8; ++ck) {
        *(float4*)&sm.Wt[wr][wc] =
            *(const float4*)&W2[(size_t)(1 + ck * 16 + wr) * H_ + wc];
        __syncthreads();
#pragma unroll
        for (int ch4 = 0; ch4 < 4; ++ch4) {
            const float4 w0v = *(const float4*)&sm.Wt[ch4 * 4 + 0][o0];
            const float4 w1v = *(const float4*)&sm.Wt[ch4 * 4 + 1][o0];
            const float4 w2v = *(const float4*)&sm.Wt[ch4 * 4 + 2][o0];
            const float4 w3v = *(const float4*)&sm.Wt[ch4 * 4 + 3][o0];
            const int cc = ck * 16 + ch4 * 4;
#pragma unroll
            for (int i = 0; i < 2; ++i) {
                const float4 zv = *(const float4*)&Zb[tm + 16 * i][cc];
                a2[i][0] += zv.x * w0v.x + zv.y * w1v.x + zv.z * w2v.x + zv.w * w3v.x;
                a2[i][1] += zv.x * w0v.y + zv.y * w1v.y + zv.z * w2v.y + zv.w * w3v.y;
                a2[i][2] += zv.x * w0v.z + zv.y * w1v.z + zv.z * w2v.z + zv.w * w3v.z;
                a2[i][3] += zv.x * w0v.w + zv.y * w1v.w + zv.z * w2v.w + zv.w * w3v.w;
            }
        }
        __syncthreads();
    }

    // ---- epilogue (verified, verbatim layout: to=tid&31, tm=tid>>5, mi=tm+16i)
    const float4 w0r = *(const float4*)&W2[o0];
    const float4 bbv = *(const float4*)&b2[o0];
    const float4 awv = *(const float4*)&aw1[o0];
    const float* __restrict__ LxRow = Lx + ((size_t)b * T_ + t) * N_ + m0;
    float* __restrict__ HnB = Hnew + (size_t)b * NH;
#pragma unroll
    for (int i = 0; i < 2; ++i) {
        const int mi = tm + 16 * i;
        const float lx = LxRow[mi];
        float c0e = tanhf(a2[i][0] + lx * w0r.x + bbv.x);
        float c1e = tanhf(a2[i][1] + lx * w0r.y + bbv.y);
        float c2e = tanhf(a2[i][2] + lx * w0r.z + bbv.z);
        float c3e = tanhf(a2[i][3] + lx * w0r.w + bbv.w);
        const int fl = (m0 + mi) * H_ + o0;
        float4 uv = *(const float4*)&Ub[fl];
        float4 hp = *(const float4*)&Hb[fl];
        float h0 = uv.x * hp.x + (1.f - uv.x) * c0e;
        float h1 = uv.y * hp.y + (1.f - uv.y) * c1e;
        float h2 = uv.z * hp.z + (1.f - uv.z) * c2e;
        float h3 = uv.w * hp.w + (1.f - uv.w) * c3e;
        *(float4*)&HnB[fl] = make_float4(h0, h1, h2, h3);
        red[mi][to] = h0 * awv.x + h1 * awv.y + h2 * awv.z + h3 * awv.w;
    }
    __syncthreads();
    if (tid < 32) {
        float s = 0.f;
#pragma unroll
        for (int k2 = 0; k2 < 32; ++k2) s += red[tid][k2];
        hs1[((size_t)b * T_ + t) * N_ + m0 + tid] = s + ab1[0];
    }
}

// ---------------------------------------------------------------------------
// beta[b,t] = softmax_t( (hs1@aw2+ab2) * (hs1@aw3+ab3) )
// ---------------------------------------------------------------------------
__global__ __launch_bounds__(64) void att_beta_kernel(
    const float* __restrict__ hs1, const float* __restrict__ aw2,
    const float* __restrict__ aw3, const float* __restrict__ ab2,
    const float* __restrict__ ab3, float* __restrict__ beta) {
    const int b = blockIdx.x;
    const int t = threadIdx.x;
    const float* __restrict__ row = hs1 + ((size_t)b * T_ + t) * N_;
    float f = 0.f, g = 0.f;
    for (int n = 0; n < N_; n += 4) {
        float4 hv = *(const float4*)&row[n];
        float4 w2v = *(const float4*)&aw2[n];
        float4 w3v = *(const float4*)&aw3[n];
        f += hv.x * w2v.x + hv.y * w2v.y + hv.z * w2v.z + hv.w * w2v.w;
        g += hv.x * w3v.x + hv.y * w3v.y + hv.z * w3v.z + hv.w * w3v.w;
    }
    f += ab2[0];
    g += ab3[0];
    float s = f * g;
    float mx = s;
    for (int off = 32; off; off >>= 1) mx = fmaxf(mx, __shfl_xor(mx, off));
    float e = expf(s - mx);
    float sum = e;
    for (int off = 32; off; off >>= 1) sum += __shfl_xor(sum, off);
    beta[b * T_ + t] = e / sum;
}

// ---------------------------------------------------------------------------
// out[b,p,n] = b_out[p] + sum_t beta[b,t]*hs1[b,t,n]*W_out[t,p]
// ---------------------------------------------------------------------------
__global__ __launch_bounds__(256) void att_out_kernel(
    const float* __restrict__ hs1, const float* __restrict__ beta,
    const float* __restrict__ Wout, const float* __restrict__ bout,
    float* __restrict__ out) {
    __shared__ float bs[T_];
    __shared__ float ws[T_][P_];
    const int b = blockIdx.x;
    const int tid = threadIdx.x;
    if (tid < T_) bs[tid] = beta[b * T_ + tid];
    for (int i = tid; i < T_ * P_; i += 256) ws[i / P_][i % P_] = Wout[i];
    __syncthreads();
    for (int nn = 0; nn < 2; ++nn) {
        const int n = tid + nn * 256;
        float acc[P_];
#pragma unroll
        for (int p = 0; p < P_; ++p) acc[p] = bout[p];
        for (int t = 0; t < T_; ++t) {
            float v = bs[t] * hs1[((size_t)b * T_ + t) * N_ + n];
#pragma unroll
            for (int p = 0; p < P_; ++p) acc[p] += v * ws[t][p];
        }
#pragma unroll
        for (int p = 0; p < P_; ++p) out[((size_t)b * P_ + p) * N_ + n] = acc[p];
    }
}

extern "C" void kernel_launch(void* const* d_in, const int* in_sizes, int n_in,
                              void* d_out, int out_size, void* d_ws, size_t ws_size,
                              hipStream_t stream) {
    const float* x = (const float*)d_in[0];
    const float* L = (const float*)d_in[1];
    const float* W1 = (const float*)d_in[2];
    const float* b1 = (const float*)d_in[3];
    const float* W2 = (const float*)d_in[4];
    const float* b2 = (const float*)d_in[5];
    const float* aw1 = (const float*)d_in[6];
    const float* aw2 = (const float*)d_in[7];
    const float* aw3 = (const float*)d_in[8];
    const float* ab1 = (const float*)d_in[9];
    const float* ab2 = (const float*)d_in[10];
    const float* ab3 = (const float*)d_in[11];
    const float* Wout = (const float*)d_in[12];
    const float* bout = (const float*)d_in[13];
    float* out = (float*)d_out;

    float* ws = (float*)d_ws;
    float* Lx = ws;                      // B*T*N
    float* hs1 = Lx + B_ * T_ * N_;      // B*T*N
    float* hb0 = hs1 + B_ * T_ * N_;     // B*N*H
    float* hb1 = hb0 + (size_t)B_ * NH;  // B*N*H
    float* rh = hb1 + (size_t)B_ * NH;   // B*N*H
    float* u = rh + (size_t)B_ * NH;     // B*N*H
    float* beta = u + (size_t)B_ * NH;   // B*T
    (void)in_sizes; (void)n_in; (void)out_size; (void)ws_size;

    hipMemsetAsync(hb0, 0, (size_t)B_ * NH * sizeof(float), stream);
    lx_kernel<<<256, 512, 0, stream>>>(x, L, Lx);

    for (int t = 0; t < T_; ++t) {
        float* hp = (t & 1) ? hb1 : hb0;
        float* hn = (t & 1) ? hb0 : hb1;
        gc1_kernel<<<256, 512, 0, stream>>>(L, hp, Lx, W1, b1, rh, u, t);
        gc2_kernel<<<256, 512, 0, stream>>>(L, hp, rh, u, Lx, W2, b2, aw1, ab1,
                                            hn, hs1, t);
    }
    att_beta_kernel<<<16, 64, 0, stream>>>(hs1, aw2, aw3, ab2, ab3, beta);
    att_out_kernel<<<16, 256, 0, stream>>>(hs1, beta, Wout, bout, out);
}

// Round 8
// 3822.941 us; speedup vs baseline: 14.1005x; 1.0484x over previous
//
#include <hip/hip_runtime.h>
#include <math.h>

#define B_ 16
#define T_ 64
#define N_ 512
#define H_ 128
#define P_ 12
#define NH 65536  // N_*H_

// ---------------------------------------------------------------------------
// Lx[b,t,m] = sum_n L[m,n] * x[b,t,n]   (L symmetric)
// ---------------------------------------------------------------------------
__global__ __launch_bounds__(512) void lx_kernel(const float* __restrict__ x,
                                                 const float* __restrict__ L,
                                                 float* __restrict__ Lx) {
    __shared__ __align__(16) float xs[4][N_];
    const int r0 = blockIdx.x * 4;
    const int tid = threadIdx.x;
    for (int j = 0; j < 4; ++j)
        xs[j][tid] = x[(size_t)(r0 + j) * N_ + tid];
    __syncthreads();
    float a0 = 0.f, a1 = 0.f, a2 = 0.f, a3 = 0.f;
    const int m = tid;
#pragma unroll 8
    for (int n = 0; n < N_; ++n) {
        float lv = L[(size_t)n * N_ + m];
        a0 += xs[0][n] * lv;
        a1 += xs[1][n] * lv;
        a2 += xs[2][n] * lv;
        a3 += xs[3][n] * lv;
    }
    Lx[(size_t)(r0 + 0) * N_ + m] = a0;
    Lx[(size_t)(r0 + 1) * N_ + m] = a1;
    Lx[(size_t)(r0 + 2) * N_ + m] = a2;
    Lx[(size_t)(r0 + 3) * N_ + m] = a3;
}

// 64-FMA quad block: acc[u][0..3][v][0..3] += A.{x,y,z,w} * Hv.{x,y,z,w}
#define FMAQ(u, v, A, Hv)                                                     \
    acc[u][0][v][0] += (A).x * (Hv).x; acc[u][0][v][1] += (A).x * (Hv).y;     \
    acc[u][0][v][2] += (A).x * (Hv).z; acc[u][0][v][3] += (A).x * (Hv).w;     \
    acc[u][1][v][0] += (A).y * (Hv).x; acc[u][1][v][1] += (A).y * (Hv).y;     \
    acc[u][1][v][2] += (A).y * (Hv).z; acc[u][1][v][3] += (A).y * (Hv).w;     \
    acc[u][2][v][0] += (A).z * (Hv).x; acc[u][2][v][1] += (A).z * (Hv).y;     \
    acc[u][2][v][2] += (A).z * (Hv).z; acc[u][2][v][3] += (A).z * (Hv).w;     \
    acc[u][3][v][0] += (A).w * (Hv).x; acc[u][3][v][1] += (A).w * (Hv).y;     \
    acc[u][3][v][2] += (A).w * (Hv).z; acc[u][3][v][3] += (A).w * (Hv).w;

// ===========================================================================
// gc1: Z = L@Hprev ; ru = sigmoid(Z@W1[1:] + Lx*W1[0] + b1)
//      flat<65536 -> rh = ru*h ; else u = ru
// grid 256 = mtile(16 of 32 rows) x b(16), b = blockIdx&15 (XCD locality, R6).
// Phase 1 retiled (R8): 8m x 8c per thread, k-split x8 (one wave = full
// 32x128 tile per k): 4 ds_read_b128 per 64 FMAs -> LDS insts 4096->2048
// (phase 1 was LDS-issue-bound 3:1, VALUBusy 35%, conflicts=0 in R7).
// Merge of 8 k-partials: 8 wave-uniform read-add-write rounds through Zb.
// NOTE: plain __launch_bounds__(512) — (512,4) forced 64 VGPRs + full spill (R3).
// NOTE: W1 MUST be staged via LDS; global-streamed W thrashed L2 (R3/R4).
// ===========================================================================
__global__ __launch_bounds__(512) void gc1_kernel(
    const float* __restrict__ L, const float* __restrict__ Hprev,
    const float* __restrict__ Lx, const float* __restrict__ W1,
    const float* __restrict__ b1, float* __restrict__ rh,
    float* __restrict__ u, int t) {
    __shared__ __align__(16) float Ht[2][32][H_];   // 32768 B
    union LW {
        float Lt[2][32][36];   // 9216 B, transposed [k][m], pitch 36 (16B-aligned rows)
        float Wt[16][260];     // 16640 B, phase-2 W chunk
    };
    __shared__ __align__(16) LW sm;
    __shared__ __align__(16) float Zb[32][H_];      // 16384 B   -> total 65792 B

    const int tid = threadIdx.x;
    const int b = blockIdx.x & 15;         // XCD-locality decode (verified R6)
    const int m0 = (blockIdx.x >> 4) * 32;
    const float* __restrict__ Hb = Hprev + (size_t)b * NH;

    // staging indices (known-good R7 pattern)
    const int hrow = tid >> 5, hcol = (tid & 31) * 4;  // 16 rows x 128 cols x2
    const int lm = tid >> 4, lk0 = (tid & 15) * 2;     // L: 32 m x 32 k (transposed)

    // ---- stage chunk 0
    {
        *(float4*)&Ht[0][hrow][hcol] = *(const float4*)&Hb[(size_t)hrow * H_ + hcol];
        *(float4*)&Ht[0][hrow + 16][hcol] =
            *(const float4*)&Hb[(size_t)(hrow + 16) * H_ + hcol];
        float2 lv = *(const float2*)&L[(size_t)(m0 + lm) * N_ + lk0];
        sm.Lt[0][lk0 + 0][lm] = lv.x;
        sm.Lt[0][lk0 + 1][lm] = lv.y;
    }
    __syncthreads();

    // ---- phase 1: k-split x8; one wave covers full 32m x 128c tile per k.
    const int g = tid >> 6;          // wave 0..7 (k-quarter within each chunk)
    const int l = tid & 63;
    const int ty = l >> 4;           // 0..3 -> m-quads {ty*4, 16+ty*4}
    const int tx = l & 15;           // 0..15 -> c-quads {tx*4, 64+tx*4}
    const int ma0 = ty * 4, mb0 = 16 + ty * 4;
    const int ca0 = tx * 4, cb0 = 64 + tx * 4;

    float acc[2][4][2][4] = {};      // [m-half][m][c-half][c]

    for (int kc = 0; kc < 16; ++kc) {
        const int bi = kc & 1, bj = bi ^ 1;
        float4 p0, p1;
        float2 pl;
        if (kc < 15) {
            const size_t kb = (size_t)(kc + 1) * 32;
            p0 = *(const float4*)&Hb[(kb + hrow) * H_ + hcol];
            p1 = *(const float4*)&Hb[(kb + hrow + 16) * H_ + hcol];
            pl = *(const float2*)&L[(size_t)(m0 + lm) * N_ + kb + lk0];
        }
#pragma unroll
        for (int kk = 0; kk < 4; ++kk) {
            const int k = g * 4 + kk;
            const float4 la0 = *(const float4*)&sm.Lt[bi][k][ma0];
            const float4 la1 = *(const float4*)&sm.Lt[bi][k][mb0];
            const float4 h0 = *(const float4*)&Ht[bi][k][ca0];
            const float4 h1 = *(const float4*)&Ht[bi][k][cb0];
            FMAQ(0, 0, la0, h0)
            FMAQ(0, 1, la0, h1)
            FMAQ(1, 0, la1, h0)
            FMAQ(1, 1, la1, h1)
        }
        if (kc < 15) {
            *(float4*)&Ht[bj][hrow][hcol] = p0;
            *(float4*)&Ht[bj][hrow + 16][hcol] = p1;
            sm.Lt[bj][lk0 + 0][lm] = pl.x;
            sm.Lt[bj][lk0 + 1][lm] = pl.y;
        }
        __syncthreads();
    }

    // ---- merge 8 k-partials: wave r adds (round 0 writes) — deterministic
    for (int r = 0; r < 8; ++r) {
        if (g == r) {
#pragma unroll
            for (int uu = 0; uu < 2; ++uu)
#pragma unroll
                for (int i = 0; i < 4; ++i) {
                    const int m = uu * 16 + ty * 4 + i;
#pragma unroll
                    for (int v = 0; v < 2; ++v) {
                        const int c = v ? cb0 : ca0;
                        float4* zp = (float4*)&Zb[m][c];
                        if (r == 0) {
                            *zp = make_float4(acc[uu][i][v][0], acc[uu][i][v][1],
                                              acc[uu][i][v][2], acc[uu][i][v][3]);
                        } else {
                            float4 z = *zp;
                            *zp = make_float4(z.x + acc[uu][i][v][0],
                                              z.y + acc[uu][i][v][1],
                                              z.z + acc[uu][i][v][2],
                                              z.w + acc[uu][i][v][3]);
                        }
                    }
                }
        }
        __syncthreads();
    }

    // ---- phase 2: out = Z @ W1[1:,:]  (W in LDS, 8 chunks of 16 ch) — R7 verbatim
    const int to = tid & 63, tm = tid >> 6;  // o0 in [0,256), 8 m-groups of 4
    const int o0 = to * 4;
    float a2[4][4] = {};
    const int wr = tid >> 5, wc = (tid & 31) * 4;

    for (int ck = 0; ck < 8; ++ck) {
        *(float4*)&sm.Wt[wr][wc] =
            *(const float4*)&W1[(size_t)(1 + ck * 16 + wr) * 256 + wc];
        *(float4*)&sm.Wt[wr][wc + 128] =
            *(const float4*)&W1[(size_t)(1 + ck * 16 + wr) * 256 + wc + 128];
        __syncthreads();
#pragma unroll
        for (int ch4 = 0; ch4 < 4; ++ch4) {
            const float4 w0v = *(const float4*)&sm.Wt[ch4 * 4 + 0][o0];
            const float4 w1v = *(const float4*)&sm.Wt[ch4 * 4 + 1][o0];
            const float4 w2v = *(const float4*)&sm.Wt[ch4 * 4 + 2][o0];
            const float4 w3v = *(const float4*)&sm.Wt[ch4 * 4 + 3][o0];
            const int cc = ck * 16 + ch4 * 4;
#pragma unroll
            for (int i = 0; i < 4; ++i) {
                const float4 zv = *(const float4*)&Zb[tm + 8 * i][cc];
                a2[i][0] += zv.x * w0v.x + zv.y * w1v.x + zv.z * w2v.x + zv.w * w3v.x;
                a2[i][1] += zv.x * w0v.y + zv.y * w1v.y + zv.z * w2v.y + zv.w * w3v.y;
                a2[i][2] += zv.x * w0v.z + zv.y * w1v.z + zv.z * w2v.z + zv.w * w3v.z;
                a2[i][3] += zv.x * w0v.w + zv.y * w1v.w + zv.z * w2v.w + zv.w * w3v.w;
            }
        }
        __syncthreads();
    }

    // ---- epilogue (verified, verbatim layout: to=tid&63, tm=tid>>6, mi=tm+8i)
    const float4 w0r = *(const float4*)&W1[o0];   // row 0 (x channel)
    const float4 bbv = *(const float4*)&b1[o0];
    const float* __restrict__ LxRow = Lx + ((size_t)b * T_ + t) * N_ + m0;
    float* __restrict__ rhB = rh + (size_t)b * NH;
    float* __restrict__ uB = u + (size_t)b * NH;
    const bool isR = (m0 < 256);
#pragma unroll
    for (int i = 0; i < 4; ++i) {
        const int mi = tm + 8 * i;
        const float lx = LxRow[mi];
        float v0 = a2[i][0] + lx * w0r.x + bbv.x;
        float v1 = a2[i][1] + lx * w0r.y + bbv.y;
        float v2 = a2[i][2] + lx * w0r.z + bbv.z;
        float v3 = a2[i][3] + lx * w0r.w + bbv.w;
        float s0 = 1.f / (1.f + expf(-v0));
        float s1 = 1.f / (1.f + expf(-v1));
        float s2 = 1.f / (1.f + expf(-v2));
        float s3 = 1.f / (1.f + expf(-v3));
        const int fl = (m0 + mi) * 256 + o0;
        if (isR) {
            float4 hv = *(const float4*)&Hb[fl];
            *(float4*)&rhB[fl] = make_float4(s0 * hv.x, s1 * hv.y, s2 * hv.z, s3 * hv.w);
        } else {
            *(float4*)&uB[fl - NH] = make_float4(s0, s1, s2, s3);
        }
    }
}

// ===========================================================================
// gc2: Z = L@rh ; c = tanh(Z@W2[1:] + Lx*W2[0] + b2) ; hn = u*h + (1-u)*c
//      hs1[b,t,m] = hn[m,:] . att_w1 + att_b1
// Same phase-1 retile as gc1; phase 2 / epilogue R7 verbatim.
// ===========================================================================
__global__ __launch_bounds__(512) void gc2_kernel(
    const float* __restrict__ L, const float* __restrict__ Hprev,
    const float* __restrict__ rh, const float* __restrict__ u,
    const float* __restrict__ Lx, const float* __restrict__ W2,
    const float* __restrict__ b2, const float* __restrict__ aw1,
    const float* __restrict__ ab1, float* __restrict__ Hnew,
    float* __restrict__ hs1, int t) {
    __shared__ __align__(16) float Ht[2][32][H_];   // 32768 B
    union LW {
        float Lt[2][32][36];   // 9216 B
        float Wt[16][132];     // 8448 B
    };
    __shared__ __align__(16) LW sm;
    __shared__ __align__(16) float Zb[32][H_];      // 16384 B
    __shared__ __align__(16) float red[32][32];     //  4096 B

    const int tid = threadIdx.x;
    const int b = blockIdx.x & 15;
    const int m0 = (blockIdx.x >> 4) * 32;
    const float* __restrict__ Rb = rh + (size_t)b * NH;
    const float* __restrict__ Hb = Hprev + (size_t)b * NH;
    const float* __restrict__ Ub = u + (size_t)b * NH;

    const int hrow = tid >> 5, hcol = (tid & 31) * 4;
    const int lm = tid >> 4, lk0 = (tid & 15) * 2;

    {
        *(float4*)&Ht[0][hrow][hcol] = *(const float4*)&Rb[(size_t)hrow * H_ + hcol];
        *(float4*)&Ht[0][hrow + 16][hcol] =
            *(const float4*)&Rb[(size_t)(hrow + 16) * H_ + hcol];
        float2 lv = *(const float2*)&L[(size_t)(m0 + lm) * N_ + lk0];
        sm.Lt[0][lk0 + 0][lm] = lv.x;
        sm.Lt[0][lk0 + 1][lm] = lv.y;
    }
    __syncthreads();

    const int g = tid >> 6;
    const int l = tid & 63;
    const int ty = l >> 4;
    const int tx = l & 15;
    const int ma0 = ty * 4, mb0 = 16 + ty * 4;
    const int ca0 = tx * 4, cb0 = 64 + tx * 4;

    float acc[2][4][2][4] = {};

    for (int kc = 0; kc < 16; ++kc) {
        const int bi = kc & 1, bj = bi ^ 1;
        float4 p0, p1;
        float2 pl;
        if (kc < 15) {
            const size_t kb = (size_t)(kc + 1) * 32;
            p0 = *(const float4*)&Rb[(kb + hrow) * H_ + hcol];
            p1 = *(const float4*)&Rb[(kb + hrow + 16) * H_ + hcol];
            pl = *(const float2*)&L[(size_t)(m0 + lm) * N_ + kb + lk0];
        }
#pragma unroll
        for (int kk = 0; kk < 4; ++kk) {
            const int k = g * 4 + kk;
            const float4 la0 = *(const float4*)&sm.Lt[bi][k][ma0];
            const float4 la1 = *(const float4*)&sm.Lt[bi][k][mb0];
            const float4 h0 = *(const float4*)&Ht[bi][k][ca0];
            const float4 h1 = *(const float4*)&Ht[bi][k][cb0];
            FMAQ(0, 0, la0, h0)
            FMAQ(0, 1, la0, h1)
            FMAQ(1, 0, la1, h0)
            FMAQ(1, 1, la1, h1)
        }
        if (kc < 15) {
            *(float4*)&Ht[bj][hrow][hcol] = p0;
            *(float4*)&Ht[bj][hrow + 16][hcol] = p1;
            sm.Lt[bj][lk0 + 0][lm] = pl.x;
            sm.Lt[bj][lk0 + 1][lm] = pl.y;
        }
        __syncthreads();
    }

    for (int r = 0; r < 8; ++r) {
        if (g == r) {
#pragma unroll
            for (int uu = 0; uu < 2; ++uu)
#pragma unroll
                for (int i = 0; i < 4; ++i) {
                    const int m = uu * 16 + ty * 4 + i;
#pragma unroll
                    for (int v = 0; v < 2; ++v) {
                        const int c = v ? cb0 : ca0;
                        float4* zp = (float4*)&Zb[m][c];
                        if (r == 0) {
                            *zp = make_float4(acc[uu][i][v][0], acc[uu][i][v][1],
                                              acc[uu][i][v][2], acc[uu][i][v][3]);
                        } else {
                            float4 z = *zp;
                            *zp = make_float4(z.x + acc[uu][i][v][0],
                                              z.y + acc[uu][i][v][1],
                                              z.z + acc[uu][i][v][2],
                                              z.w + acc[uu][i][v][3]);
                        }
                    }
                }
        }
        __syncthreads();
    }

    // ---- phase 2: O=128, 2m x 4o per thread, W2 in LDS (8 chunks of 16 ch)
    const int to = tid & 31, tm = tid >> 5;   // 16 m-groups of 2
    const int o0 = to * 4;
    float a2[2][4] = {};
    const int wr = tid >> 5, wc = (tid & 31) * 4;

    for (int ck = 0; ck < 8; ++ck) {
        *(float4*)&sm.Wt[wr][wc] =
            *(const float4*)&W2[(size_t)(1 + ck * 16 + wr) * H_ + wc];
        __syncthreads();
#pragma unroll
        for (int ch4 = 0; ch4 < 4; ++ch4) {
            const float4 w0v = *(const float4*)&sm.Wt[ch4 * 4 + 0][o0];
            const float4 w1v = *(const float4*)&sm.Wt[ch4 * 4 + 1][o0];
            const float4 w2v = *(const float4*)&sm.Wt[ch4 * 4 + 2][o0];
            const float4 w3v = *(const float4*)&sm.Wt[ch4 * 4 + 3][o0];
            const int cc = ck * 16 + ch4 * 4;
#pragma unroll
            for (int i = 0; i < 2; ++i) {
                const float4 zv = *(const float4*)&Zb[tm + 16 * i][cc];
                a2[i][0] += zv.x * w0v.x + zv.y * w1v.x + zv.z * w2v.x + zv.w * w3v.x;
                a2[i][1] += zv.x * w0v.y + zv.y * w1v.y + zv.z * w2v.y + zv.w * w3v.y;
                a2[i][2] += zv.x * w0v.z + zv.y * w1v.z + zv.z * w2v.z + zv.w * w3v.z;
                a2[i][3] += zv.x * w0v.w + zv.y * w1v.w + zv.z * w2v.w + zv.w * w3v.w;
            }
        }
        __syncthreads();
    }

    // ---- epilogue (verified, verbatim layout: to=tid&31, tm=tid>>5, mi=tm+16i)
    const float4 w0r = *(const float4*)&W2[o0];
    const float4 bbv = *(const float4*)&b2[o0];
    const float4 awv = *(const float4*)&aw1[o0];
    const float* __restrict__ LxRow = Lx + ((size_t)b * T_ + t) * N_ + m0;
    float* __restrict__ HnB = Hnew + (size_t)b * NH;
#pragma unroll
    for (int i = 0; i < 2; ++i) {
        const int mi = tm + 16 * i;
        const float lx = LxRow[mi];
        float c0e = tanhf(a2[i][0] + lx * w0r.x + bbv.x);
        float c1e = tanhf(a2[i][1] + lx * w0r.y + bbv.y);
        float c2e = tanhf(a2[i][2] + lx * w0r.z + bbv.z);
        float c3e = tanhf(a2[i][3] + lx * w0r.w + bbv.w);
        const int fl = (m0 + mi) * H_ + o0;
        float4 uv = *(const float4*)&Ub[fl];
        float4 hp = *(const float4*)&Hb[fl];
        float h0 = uv.x * hp.x + (1.f - uv.x) * c0e;
        float h1 = uv.y * hp.y + (1.f - uv.y) * c1e;
        float h2 = uv.z * hp.z + (1.f - uv.z) * c2e;
        float h3 = uv.w * hp.w + (1.f - uv.w) * c3e;
        *(float4*)&HnB[fl] = make_float4(h0, h1, h2, h3);
        red[mi][to] = h0 * awv.x + h1 * awv.y + h2 * awv.z + h3 * awv.w;
    }
    __syncthreads();
    if (tid < 32) {
        float s = 0.f;
#pragma unroll
        for (int k2 = 0; k2 < 32; ++k2) s += red[tid][k2];
        hs1[((size_t)b * T_ + t) * N_ + m0 + tid] = s + ab1[0];
    }
}

// ---------------------------------------------------------------------------
// beta[b,t] = softmax_t( (hs1@aw2+ab2) * (hs1@aw3+ab3) )
// ---------------------------------------------------------------------------
__global__ __launch_bounds__(64) void att_beta_kernel(
    const float* __restrict__ hs1, const float* __restrict__ aw2,
    const float* __restrict__ aw3, const float* __restrict__ ab2,
    const float* __restrict__ ab3, float* __restrict__ beta) {
    const int b = blockIdx.x;
    const int t = threadIdx.x;
    const float* __restrict__ row = hs1 + ((size_t)b * T_ + t) * N_;
    float f = 0.f, g = 0.f;
    for (int n = 0; n < N_; n += 4) {
        float4 hv = *(const float4*)&row[n];
        float4 w2v = *(const float4*)&aw2[n];
        float4 w3v = *(const float4*)&aw3[n];
        f += hv.x * w2v.x + hv.y * w2v.y + hv.z * w2v.z + hv.w * w2v.w;
        g += hv.x * w3v.x + hv.y * w3v.y + hv.z * w3v.z + hv.w * w3v.w;
    }
    f += ab2[0];
    g += ab3[0];
    float s = f * g;
    float mx = s;
    for (int off = 32; off; off >>= 1) mx = fmaxf(mx, __shfl_xor(mx, off));
    float e = expf(s - mx);
    float sum = e;
    for (int off = 32; off; off >>= 1) sum += __shfl_xor(sum, off);
    beta[b * T_ + t] = e / sum;
}

// ---------------------------------------------------------------------------
// out[b,p,n] = b_out[p] + sum_t beta[b,t]*hs1[b,t,n]*W_out[t,p]
// ---------------------------------------------------------------------------
__global__ __launch_bounds__(256) void att_out_kernel(
    const float* __restrict__ hs1, const float* __restrict__ beta,
    const float* __restrict__ Wout, const float* __restrict__ bout,
    float* __restrict__ out) {
    __shared__ float bs[T_];
    __shared__ float ws[T_][P_];
    const int b = blockIdx.x;
    const int tid = threadIdx.x;
    if (tid < T_) bs[tid] = beta[b * T_ + tid];
    for (int i = tid; i < T_ * P_; i += 256) ws[i / P_][i % P_] = Wout[i];
    __syncthreads();
    for (int nn = 0; nn < 2; ++nn) {
        const int n = tid + nn * 256;
        float acc[P_];
#pragma unroll
        for (int p = 0; p < P_; ++p) acc[p] = bout[p];
        for (int t = 0; t < T_; ++t) {
            float v = bs[t] * hs1[((size_t)b * T_ + t) * N_ + n];
#pragma unroll
            for (int p = 0; p < P_; ++p) acc[p] += v * ws[t][p];
        }
#pragma unroll
        for (int p = 0; p < P_; ++p) out[((size_t)b * P_ + p) * N_ + n] = acc[p];
    }
}

extern "C" void kernel_launch(void* const* d_in, const int* in_sizes, int n_in,
                              void* d_out, int out_size, void* d_ws, size_t ws_size,
                              hipStream_t stream) {
    const float* x = (const float*)d_in[0];
    const float* L = (const float*)d_in[1];
    const float* W1 = (const float*)d_in[2];
    const float* b1 = (const float*)d_in[3];
    const float* W2 = (const float*)d_in[4];
    const float* b2 = (const float*)d_in[5];
    const float* aw1 = (const float*)d_in[6];
    const float* aw2 = (const float*)d_in[7];
    const float* aw3 = (const float*)d_in[8];
    const float* ab1 = (const float*)d_in[9];
    const float* ab2 = (const float*)d_in[10];
    const float* ab3 = (const float*)d_in[11];
    const float* Wout = (const float*)d_in[12];
    const float* bout = (const float*)d_in[13];
    float* out = (float*)d_out;

    float* ws = (float*)d_ws;
    float* Lx = ws;                      // B*T*N
    float* hs1 = Lx + B_ * T_ * N_;      // B*T*N
    float* hb0 = hs1 + B_ * T_ * N_;     // B*N*H
    float* hb1 = hb0 + (size_t)B_ * NH;  // B*N*H
    float* rh = hb1 + (size_t)B_ * NH;   // B*N*H
    float* u = rh + (size_t)B_ * NH;     // B*N*H
    float* beta = u + (size_t)B_ * NH;   // B*T
    (void)in_sizes; (void)n_in; (void)out_size; (void)ws_size;

    hipMemsetAsync(hb0, 0, (size_t)B_ * NH * sizeof(float), stream);
    lx_kernel<<<256, 512, 0, stream>>>(x, L, Lx);

    for (int t = 0; t < T_; ++t) {
        float* hp = (t & 1) ? hb1 : hb0;
        float* hn = (t & 1) ? hb0 : hb1;
        gc1_kernel<<<256, 512, 0, stream>>>(L, hp, Lx, W1, b1, rh, u, t);
        gc2_kernel<<<256, 512, 0, stream>>>(L, hp, rh, u, Lx, W2, b2, aw1, ab1,
                                            hn, hs1, t);
    }
    att_beta_kernel<<<16, 64, 0, stream>>>(hs1, aw2, aw3, ab2, ab3, beta);
    att_out_kernel<<<16, 256, 0, stream>>>(hs1, beta, Wout, bout, out);
}